// Round 9
// baseline (286.917 us; speedup 1.0000x reference)
//
#include <hip/hip_runtime.h>
#include <math.h>

#define BB 8
#define SS 2048
#define NTOK (BB * SS)   // 16384
#define ATB_SPLIT 16

using bf16x8 = __attribute__((ext_vector_type(8))) short;
using f32x4  = __attribute__((ext_vector_type(4))) float;

__device__ __forceinline__ float gelu_tanh(float x) {
    float y = 0.7978845608f * (x + 0.044715f * x * x * x);
    float e = __expf(2.0f * y);
    float t = 1.0f - 2.0f / (e + 1.0f);
    return 0.5f * x * (1.0f + t);
}
__device__ __forceinline__ unsigned short f2b(float f) {
    unsigned int u = __float_as_uint(f);
    u += 0x7FFFu + ((u >> 16) & 1u);
    return (unsigned short)(u >> 16);
}
__device__ __forceinline__ float b2f(unsigned short u) {
    return __uint_as_float((unsigned int)u << 16);
}
__device__ __forceinline__ bf16x8 ldg_f32_b8(const float* p) {
    float4 f0 = *(const float4*)p, f1 = *(const float4*)(p + 4);
    union { ushort4 u[2]; bf16x8 v; } r;
    r.u[0] = (ushort4){f2b(f0.x), f2b(f0.y), f2b(f0.z), f2b(f0.w)};
    r.u[1] = (ushort4){f2b(f1.x), f2b(f1.y), f2b(f1.z), f2b(f1.w)};
    return r.v;
}

// ---------------------------------------------------------------------------
// Phase A: bx<256 -> fused window block (self-converting weights);
//          bx>=256 -> convert ffn weights fp32->bf16 into Wb.
// ---------------------------------------------------------------------------
__global__ __launch_bounds__(256) void phaseA(
    const float* __restrict__ x,
    const float* __restrict__ lw_in_w, const float* __restrict__ b_in,
    const float* __restrict__ lw_out_w, const float* __restrict__ b_out,
    const float* __restrict__ lng, const float* __restrict__ lnb,
    float* __restrict__ x1, unsigned short* __restrict__ x1b,
    const float* __restrict__ ffn_w1, const float* __restrict__ ffn_w2,
    unsigned short* __restrict__ Wb)
{
    __shared__ unsigned short Qs[64 * 136];   // Q; attn-out in-place
    __shared__ unsigned short Ks[64 * 136];
    __shared__ unsigned short Vt[128 * 72];
    __shared__ unsigned short Pb[4][32 * 72];
    __shared__ float red[2][64][2];
    const int tid = threadIdx.x;

    if (blockIdx.x >= 256) {   // ---- convW role ----
        int i = (blockIdx.x - 256) * 256 + tid;   // 0..131071
        float v = (i < 65536) ? ffn_w1[i] : ffn_w2[i - 65536];
        Wb[i] = f2b(v);
        return;
    }

    const int m0 = blockIdx.x * 64;
    const int wv = tid >> 6, lane = tid & 63, ln = lane & 15, q = lane >> 4;
    const int wm = (wv >> 1) * 32, wn = (wv & 1) * 64;

    bf16x8 afr[4][2];
    #pragma unroll
    for (int kf = 0; kf < 4; ++kf)
        #pragma unroll
        for (int fm = 0; fm < 2; ++fm)
            afr[kf][fm] = ldg_f32_b8(x + (size_t)(m0 + wm + fm * 16 + ln) * 128 + kf * 32 + q * 8);

    #pragma unroll
    for (int p = 0; p < 3; ++p) {
        f32x4 acc[2][4] = {};
        #pragma unroll
        for (int kf = 0; kf < 4; ++kf) {
            bf16x8 b[4];
            #pragma unroll
            for (int fn = 0; fn < 4; ++fn)
                b[fn] = ldg_f32_b8(lw_in_w + (size_t)(p * 128 + wn + fn * 16 + ln) * 128 + kf * 32 + q * 8);
            #pragma unroll
            for (int fm = 0; fm < 2; ++fm)
                #pragma unroll
                for (int fn = 0; fn < 4; ++fn)
                    acc[fm][fn] = __builtin_amdgcn_mfma_f32_16x16x32_bf16(afr[kf][fm], b[fn], acc[fm][fn], 0, 0, 0);
        }
        #pragma unroll
        for (int fm = 0; fm < 2; ++fm)
            #pragma unroll
            for (int r = 0; r < 4; ++r) {
                int rl = wm + fm * 16 + q * 4 + r;
                #pragma unroll
                for (int fn = 0; fn < 4; ++fn) {
                    int col = wn + fn * 16 + ln;
                    unsigned short v = f2b(acc[fm][fn][r] + b_in[p * 128 + col]);
                    if (p == 0)      Qs[rl * 136 + col] = v;
                    else if (p == 1) Ks[rl * 136 + col] = v;
                    else             Vt[col * 72 + rl] = v;
                }
            }
    }
    __syncthreads();

    // ---- MFMA attention: wave = (m-half mh, head-quad hq) ----
    {
        const int mh = wv >> 1, hq = wv & 1;
        unsigned short* P = &Pb[wv][0];
        #pragma unroll
        for (int hh = 0; hh < 4; ++hh) {
            const int h = hq * 4 + hh;
            f32x4 sacc[2][4] = {};
            bf16x8 az[2] = {}, bz[4] = {};
            if (q < 2) {
                #pragma unroll
                for (int fm = 0; fm < 2; ++fm)
                    az[fm] = *(const bf16x8*)&Qs[(mh * 32 + fm * 16 + ln) * 136 + h * 16 + q * 8];
                #pragma unroll
                for (int fn = 0; fn < 4; ++fn)
                    bz[fn] = *(const bf16x8*)&Ks[(fn * 16 + ln) * 136 + h * 16 + q * 8];
            }
            #pragma unroll
            for (int fm = 0; fm < 2; ++fm)
                #pragma unroll
                for (int fn = 0; fn < 4; ++fn)
                    sacc[fm][fn] = __builtin_amdgcn_mfma_f32_16x16x32_bf16(az[fm], bz[fn], sacc[fm][fn], 0, 0, 0);
            float invr[2][4];
            #pragma unroll
            for (int fm = 0; fm < 2; ++fm)
                #pragma unroll
                for (int r = 0; r < 4; ++r) {
                    int gi = mh * 32 + fm * 16 + q * 4 + r;
                    float mx = -1e30f;
                    #pragma unroll
                    for (int fn = 0; fn < 4; ++fn) {
                        int j = fn * 16 + ln;
                        float s = sacc[fm][fn][r] * 0.25f;
                        if (j > gi) s = -1e30f;
                        sacc[fm][fn][r] = s;
                        mx = fmaxf(mx, s);
                    }
                    #pragma unroll
                    for (int off = 1; off < 16; off <<= 1)
                        mx = fmaxf(mx, __shfl_xor(mx, off, 64));
                    float sum = 0.0f;
                    #pragma unroll
                    for (int fn = 0; fn < 4; ++fn) {
                        float p_ = __expf(sacc[fm][fn][r] - mx);
                        sacc[fm][fn][r] = p_;
                        sum += p_;
                    }
                    #pragma unroll
                    for (int off = 1; off < 16; off <<= 1)
                        sum += __shfl_xor(sum, off, 64);
                    invr[fm][r] = 1.0f / sum;
                    #pragma unroll
                    for (int fn = 0; fn < 4; ++fn)
                        P[(fm * 16 + q * 4 + r) * 72 + fn * 16 + ln] = f2b(sacc[fm][fn][r]);
                }
            f32x4 oacc[2] = {};
            #pragma unroll
            for (int kf2 = 0; kf2 < 2; ++kf2) {
                bf16x8 pa[2], vb;
                #pragma unroll
                for (int fm = 0; fm < 2; ++fm)
                    pa[fm] = *(const bf16x8*)&P[(fm * 16 + ln) * 72 + kf2 * 32 + q * 8];
                vb = *(const bf16x8*)&Vt[(h * 16 + ln) * 72 + kf2 * 32 + q * 8];
                #pragma unroll
                for (int fm = 0; fm < 2; ++fm)
                    oacc[fm] = __builtin_amdgcn_mfma_f32_16x16x32_bf16(pa[fm], vb, oacc[fm], 0, 0, 0);
            }
            #pragma unroll
            for (int fm = 0; fm < 2; ++fm)
                #pragma unroll
                for (int r = 0; r < 4; ++r)
                    Qs[(mh * 32 + fm * 16 + q * 4 + r) * 136 + h * 16 + ln] =
                        f2b(oacc[fm][r] * invr[fm][r]);
        }
    }
    __syncthreads();

    // ---- out-proj + residual(x) + LN1 ----
    f32x4 acc[2][4] = {};
    #pragma unroll
    for (int kf = 0; kf < 4; ++kf) {
        bf16x8 a[2], b[4];
        #pragma unroll
        for (int fm = 0; fm < 2; ++fm)
            a[fm] = *(const bf16x8*)&Qs[(wm + fm * 16 + ln) * 136 + kf * 32 + q * 8];
        #pragma unroll
        for (int fn = 0; fn < 4; ++fn)
            b[fn] = ldg_f32_b8(lw_out_w + (size_t)(wn + fn * 16 + ln) * 128 + kf * 32 + q * 8);
        #pragma unroll
        for (int fm = 0; fm < 2; ++fm)
            #pragma unroll
            for (int fn = 0; fn < 4; ++fn)
                acc[fm][fn] = __builtin_amdgcn_mfma_f32_16x16x32_bf16(a[fm], b[fn], acc[fm][fn], 0, 0, 0);
    }
    #pragma unroll
    for (int fm = 0; fm < 2; ++fm)
        #pragma unroll
        for (int r = 0; r < 4; ++r) {
            int rl = wm + fm * 16 + q * 4 + r;
            int row = m0 + rl;
            float s1 = 0.0f, s2 = 0.0f;
            #pragma unroll
            for (int fn = 0; fn < 4; ++fn) {
                int col = wn + fn * 16 + ln;
                float vv = acc[fm][fn][r] + b_out[col] + x[(size_t)row * 128 + col];
                acc[fm][fn][r] = vv;
                s1 += vv; s2 += vv * vv;
            }
            #pragma unroll
            for (int off = 1; off < 16; off <<= 1) {
                s1 += __shfl_xor(s1, off, 64);
                s2 += __shfl_xor(s2, off, 64);
            }
            if (ln == 0) { red[0][rl][wv & 1] = s1; red[1][rl][wv & 1] = s2; }
        }
    __syncthreads();
    #pragma unroll
    for (int fm = 0; fm < 2; ++fm)
        #pragma unroll
        for (int r = 0; r < 4; ++r) {
            int rl = wm + fm * 16 + q * 4 + r;
            int row = m0 + rl;
            float mu = (red[0][rl][0] + red[0][rl][1]) * (1.0f / 128.0f);
            float var = (red[1][rl][0] + red[1][rl][1]) * (1.0f / 128.0f) - mu * mu;
            float rs = rsqrtf(var + 1e-5f);
            #pragma unroll
            for (int fn = 0; fn < 4; ++fn) {
                int col = wn + fn * 16 + ln;
                float o = (acc[fm][fn][r] - mu) * rs * lng[col] + lnb[col];
                x1[(size_t)row * 128 + col] = o;
                x1b[(size_t)row * 128 + col] = f2b(o);
            }
        }
}

// ---------------------------------------------------------------------------
// Phase B (barrier-free): bx<256 -> FFN, each wave owns 16 full rows
// (h in per-wave LDS, LN2 via 16-lane shfl only);
// bx>=256 -> stproj, each wave owns 16 full rows (within-wave cosnorm).
// ---------------------------------------------------------------------------
__global__ __launch_bounds__(256) void phaseB(
    const unsigned short* __restrict__ x1b, const float* __restrict__ x1,
    const unsigned short* __restrict__ Wb,
    const float* __restrict__ b1, const float* __restrict__ b2,
    const float* __restrict__ lng, const float* __restrict__ lnb,
    float* __restrict__ x2,
    const float* __restrict__ spatial, const float* __restrict__ temporal,
    const float* __restrict__ spat_w, const float* __restrict__ temp_w,
    const float* __restrict__ bsp, const float* __restrict__ btp,
    unsigned short* __restrict__ snb, unsigned short* __restrict__ tnb,
    unsigned short* __restrict__ seb, unsigned short* __restrict__ teb)
{
    __shared__ unsigned short HsP[4][16 * 72];   // per-wave private h buffer
    const int tid = threadIdx.x;
    const int wv = tid >> 6, lane = tid & 63, ln = lane & 15, q = lane >> 4;

    if (blockIdx.x < 256) {   // ---- FFN role: rows t0+wv*16 .. +16 ----
        const int r0 = blockIdx.x * 64 + wv * 16;
        const unsigned short* w1 = Wb;            // (512,128)
        const unsigned short* w2 = Wb + 65536;    // (128,512)
        unsigned short* Hp = &HsP[wv][0];

        bf16x8 xa[4];
        #pragma unroll
        for (int kf = 0; kf < 4; ++kf)
            xa[kf] = *(const bf16x8*)&x1b[(size_t)(r0 + ln) * 128 + kf * 32 + q * 8];

        f32x4 acc2[8] = {};
        #pragma unroll
        for (int ch = 0; ch < 8; ++ch) {
            const int hc0 = ch * 64;
            f32x4 acc1[4] = {};
            #pragma unroll
            for (int kf = 0; kf < 4; ++kf)
                #pragma unroll
                for (int fn = 0; fn < 4; ++fn) {
                    bf16x8 bb = *(const bf16x8*)&w1[(size_t)(hc0 + fn * 16 + ln) * 128 + kf * 32 + q * 8];
                    acc1[fn] = __builtin_amdgcn_mfma_f32_16x16x32_bf16(xa[kf], bb, acc1[fn], 0, 0, 0);
                }
            #pragma unroll
            for (int fn = 0; fn < 4; ++fn)
                #pragma unroll
                for (int r = 0; r < 4; ++r) {
                    int col = fn * 16 + ln;
                    Hp[(q * 4 + r) * 72 + col] = f2b(gelu_tanh(acc1[fn][r] + b1[hc0 + col]));
                }
            // same-wave LDS readback (compiler inserts lgkmcnt; no barrier)
            #pragma unroll
            for (int kf2 = 0; kf2 < 2; ++kf2) {
                bf16x8 ha = *(const bf16x8*)&Hp[ln * 72 + kf2 * 32 + q * 8];
                #pragma unroll
                for (int fn = 0; fn < 8; ++fn) {
                    bf16x8 bb = *(const bf16x8*)&w2[(size_t)(fn * 16 + ln) * 512 + hc0 + kf2 * 32 + q * 8];
                    acc2[fn] = __builtin_amdgcn_mfma_f32_16x16x32_bf16(ha, bb, acc2[fn], 0, 0, 0);
                }
            }
        }
        // epilogue: +b2 +x1, LN2 (within-wave: rows live in this wave only)
        #pragma unroll
        for (int r = 0; r < 4; ++r) {
            int row = r0 + q * 4 + r;
            float s1 = 0.0f, s2 = 0.0f;
            float vv[8];
            #pragma unroll
            for (int fn = 0; fn < 8; ++fn) {
                int col = fn * 16 + ln;
                vv[fn] = acc2[fn][r] + b2[col] + x1[(size_t)row * 128 + col];
                s1 += vv[fn]; s2 += vv[fn] * vv[fn];
            }
            #pragma unroll
            for (int off = 1; off < 16; off <<= 1) {
                s1 += __shfl_xor(s1, off, 64);
                s2 += __shfl_xor(s2, off, 64);
            }
            float mu = s1 * (1.0f / 128.0f);
            float var = s2 * (1.0f / 128.0f) - mu * mu;
            float rs = rsqrtf(var + 1e-5f);
            #pragma unroll
            for (int fn = 0; fn < 8; ++fn) {
                int col = fn * 16 + ln;
                x2[(size_t)row * 128 + col] = (vv[fn] - mu) * rs * lng[col] + lnb[col];
            }
        }
        return;
    }

    // ---- stproj role: rows m0+wv*16 .. +16 of one tensor ----
    {
        const int idx2 = blockIdx.x - 256;        // 0..511
        const int y = idx2 >> 8;                  // 0 spatial, 1 temporal
        const int r0 = (idx2 & 255) * 64 + wv * 16;
        const float* Af = y ? temporal : spatial;
        const float* Wf = y ? temp_w : spat_w;
        const float* bias = y ? btp : bsp;
        unsigned short* nb = y ? tnb : snb;
        unsigned short* raw = y ? teb : seb;

        bf16x8 a[4];
        #pragma unroll
        for (int kf = 0; kf < 4; ++kf)
            a[kf] = ldg_f32_b8(Af + (size_t)(r0 + ln) * 128 + kf * 32 + q * 8);

        f32x4 acc[8] = {};
        #pragma unroll
        for (int kf = 0; kf < 4; ++kf)
            #pragma unroll
            for (int fn = 0; fn < 8; ++fn) {
                bf16x8 bb = ldg_f32_b8(Wf + (size_t)(fn * 16 + ln) * 128 + kf * 32 + q * 8);
                acc[fn] = __builtin_amdgcn_mfma_f32_16x16x32_bf16(a[kf], bb, acc[fn], 0, 0, 0);
            }
        #pragma unroll
        for (int r = 0; r < 4; ++r) {
            int row = r0 + q * 4 + r;
            float s2 = 0.0f;
            float vv[8];
            #pragma unroll
            for (int fn = 0; fn < 8; ++fn) {
                vv[fn] = acc[fn][r] + bias[fn * 16 + ln];
                s2 += vv[fn] * vv[fn];
            }
            #pragma unroll
            for (int off = 1; off < 16; off <<= 1) s2 += __shfl_xor(s2, off, 64);
            float inv = 1.0f / fmaxf(sqrtf(s2), 1e-8f);
            #pragma unroll
            for (int fn = 0; fn < 8; ++fn) {
                int col = fn * 16 + ln;
                nb[(size_t)row * 128 + col] = f2b(vv[fn] * inv);
                raw[(size_t)row * 128 + col] = f2b(vv[fn]);
            }
        }
    }
}

// ---------------------------------------------------------------------------
// Split-K A^T B per batch, bf16 in / fp32 accumulate.
// ---------------------------------------------------------------------------
__global__ __launch_bounds__(256) void atb_split_kernel(
    const unsigned short* __restrict__ snb, const unsigned short* __restrict__ tnb,
    float* __restrict__ part)
{
    const int b = blockIdx.z / ATB_SPLIT;
    const int chunk = blockIdx.z % ATB_SPLIT;
    const int d0 = blockIdx.x * 64, e0 = blockIdx.y * 64;
    __shared__ float Ss[32][68];
    __shared__ float Ts[32][68];
    const int tid = threadIdx.x;
    const int tx = tid % 16, ty = tid / 16;
    const int jbase = chunk * (SS / ATB_SPLIT);
    float acc[4][4] = {};
    for (int j0 = jbase; j0 < jbase + SS / ATB_SPLIT; j0 += 32) {
        {
            int r = tid >> 3, c8 = (tid & 7) * 8;
            uint4 sv = *(const uint4*)&snb[(size_t)(b * SS + j0 + r) * 128 + d0 + c8];
            uint4 tv = *(const uint4*)&tnb[(size_t)(b * SS + j0 + r) * 128 + e0 + c8];
            const unsigned short* sp = (const unsigned short*)&sv;
            const unsigned short* tp = (const unsigned short*)&tv;
            #pragma unroll
            for (int c = 0; c < 8; ++c) {
                Ss[r][c8 + c] = b2f(sp[c]);
                Ts[r][c8 + c] = b2f(tp[c]);
            }
        }
        __syncthreads();
        #pragma unroll
        for (int kk = 0; kk < 32; ++kk) {
            float4 af = *(const float4*)&Ss[kk][ty * 4];
            float4 wf = *(const float4*)&Ts[kk][tx * 4];
            float a[4] = {af.x, af.y, af.z, af.w};
            float w[4] = {wf.x, wf.y, wf.z, wf.w};
            #pragma unroll
            for (int i = 0; i < 4; ++i)
                #pragma unroll
                for (int j = 0; j < 4; ++j)
                    acc[i][j] = fmaf(a[i], w[j], acc[i][j]);
        }
        __syncthreads();
    }
    float* pp = part + (size_t)(b * ATB_SPLIT + chunk) * 16384;
    #pragma unroll
    for (int i = 0; i < 4; ++i) {
        float4 ov = {acc[i][0], acc[i][1], acc[i][2], acc[i][3]};
        *(float4*)&pp[(size_t)(d0 + ty * 4 + i) * 128 + e0 + tx * 4] = ov;
    }
}

// Mtb[b][e*128+d] = bf16( sum_chunk part[(b*16+c)*16384 + d*128 + e] )
__global__ __launch_bounds__(256) void atb_reduce_kernel(
    const float* __restrict__ part, unsigned short* __restrict__ Mtb)
{
    int i = blockIdx.x * 256 + threadIdx.x;   // 0..131071
    int b = i >> 14, rem = i & 16383;
    int e = rem >> 7, d = rem & 127;
    const float* pp = part + (size_t)b * ATB_SPLIT * 16384 + (size_t)d * 128 + e;
    float s = 0.0f;
    #pragma unroll
    for (int c = 0; c < ATB_SPLIT; ++c) s += pp[(size_t)c * 16384];
    Mtb[i] = f2b(s);
}

// ---------------------------------------------------------------------------
// sim[row] = (1/S) <snb@M_b, tnb>_row via MFMA; frags direct from global.
// ---------------------------------------------------------------------------
__global__ __launch_bounds__(256) void simgemm_kernel(
    const unsigned short* __restrict__ snb, const unsigned short* __restrict__ tnb,
    const unsigned short* __restrict__ Mtb, float* __restrict__ sim)
{
    __shared__ float red[64][2];
    const int tid = threadIdx.x, m0 = blockIdx.x * 64, b = m0 >> 11;
    const int wv = tid >> 6, lane = tid & 63, ln = lane & 15, q = lane >> 4;
    const int wm = (wv >> 1) * 32, wn = (wv & 1) * 64;

    f32x4 acc[2][4] = {};
    #pragma unroll
    for (int kf = 0; kf < 4; ++kf) {
        bf16x8 a[2], bb[4];
        #pragma unroll
        for (int fm = 0; fm < 2; ++fm)
            a[fm] = *(const bf16x8*)&snb[(size_t)(m0 + wm + fm * 16 + ln) * 128 + kf * 32 + q * 8];
        #pragma unroll
        for (int fn = 0; fn < 4; ++fn)
            bb[fn] = *(const bf16x8*)&Mtb[(size_t)b * 16384 + (size_t)(wn + fn * 16 + ln) * 128 + kf * 32 + q * 8];
        #pragma unroll
        for (int fm = 0; fm < 2; ++fm)
            #pragma unroll
            for (int fn = 0; fn < 4; ++fn)
                acc[fm][fn] = __builtin_amdgcn_mfma_f32_16x16x32_bf16(a[fm], bb[fn], acc[fm][fn], 0, 0, 0);
    }
    #pragma unroll
    for (int fm = 0; fm < 2; ++fm)
        #pragma unroll
        for (int r = 0; r < 4; ++r) {
            int rl = wm + fm * 16 + q * 4 + r;
            int row = m0 + rl;
            float s = 0.0f;
            #pragma unroll
            for (int fn = 0; fn < 4; ++fn) {
                int col = wn + fn * 16 + ln;
                s += acc[fm][fn][r] * b2f(tnb[(size_t)row * 128 + col]);
            }
            #pragma unroll
            for (int off = 1; off < 16; off <<= 1) s += __shfl_xor(s, off, 64);
            if (ln == 0) red[rl][wv & 1] = s;
        }
    __syncthreads();
    if (tid < 64) sim[m0 + tid] = (red[tid][0] + red[tid][1]) * (1.0f / (float)SS);
}

// ---------------------------------------------------------------------------
// Fused interaction block (self-converting weights).
// ---------------------------------------------------------------------------
__global__ __launch_bounds__(256) void inter_block(
    const unsigned short* __restrict__ seb, const unsigned short* __restrict__ teb,
    const float* __restrict__ Wint,  // (384,128) fp32
    const float* __restrict__ b_int,
    const float* __restrict__ Wio,   // (128,128) fp32
    const float* __restrict__ b_io,
    const float* __restrict__ sim, const float* __restrict__ x2,
    float* __restrict__ out)
{
    __shared__ unsigned short Qs[64 * 136];
    __shared__ unsigned short KVs[64 * 256];
    const int tid = threadIdx.x, s0 = blockIdx.x * 8;
    const int wv = tid >> 6, lane = tid & 63, ln = lane & 15, q = lane >> 4;
    const int wm = (wv >> 1) * 32, wn = (wv & 1) * 64;

    bf16x8 afr[4][2];
    #pragma unroll
    for (int kf = 0; kf < 4; ++kf)
        #pragma unroll
        for (int fm = 0; fm < 2; ++fm) {
            int rl = wm + fm * 16 + ln;
            size_t g = (size_t)(rl >> 3) * 2048 + s0 + (rl & 7);
            afr[kf][fm] = *(const bf16x8*)&seb[g * 128 + kf * 32 + q * 8];
        }

    #pragma unroll
    for (int p = 0; p < 3; ++p) {
        if (p == 1) {
            #pragma unroll
            for (int kf = 0; kf < 4; ++kf)
                #pragma unroll
                for (int fm = 0; fm < 2; ++fm) {
                    int rl = wm + fm * 16 + ln;
                    size_t g = (size_t)(rl >> 3) * 2048 + s0 + (rl & 7);
                    afr[kf][fm] = *(const bf16x8*)&teb[g * 128 + kf * 32 + q * 8];
                }
        }
        f32x4 acc[2][4] = {};
        #pragma unroll
        for (int kf = 0; kf < 4; ++kf) {
            bf16x8 b[4];
            #pragma unroll
            for (int fn = 0; fn < 4; ++fn)
                b[fn] = ldg_f32_b8(Wint + (size_t)(p * 128 + wn + fn * 16 + ln) * 128 + kf * 32 + q * 8);
            #pragma unroll
            for (int fm = 0; fm < 2; ++fm)
                #pragma unroll
                for (int fn = 0; fn < 4; ++fn)
                    acc[fm][fn] = __builtin_amdgcn_mfma_f32_16x16x32_bf16(afr[kf][fm], b[fn], acc[fm][fn], 0, 0, 0);
        }
        #pragma unroll
        for (int fm = 0; fm < 2; ++fm)
            #pragma unroll
            for (int r = 0; r < 4; ++r) {
                int rl = wm + fm * 16 + q * 4 + r;
                #pragma unroll
                for (int fn = 0; fn < 4; ++fn) {
                    int col = wn + fn * 16 + ln;
                    unsigned short v = f2b(acc[fm][fn][r] + b_int[p * 128 + col]);
                    if (p == 0) Qs[rl * 136 + col] = v;
                    else        KVs[rl * 256 + (p - 1) * 128 + col] = v;
                }
            }
        __syncthreads();
    }

    #pragma unroll
    for (int tt = 0; tt < 2; ++tt) {
        int task = tid + tt * 256;
        int ss = task >> 6, h = (task >> 3) & 7, i = task & 7;
        int rq = i * 8 + ss;
        float qr[16];
        {
            uint4 q0 = *(const uint4*)&Qs[rq * 136 + h * 16];
            uint4 q1 = *(const uint4*)&Qs[rq * 136 + h * 16 + 8];
            const unsigned short* p0 = (const unsigned short*)&q0;
            const unsigned short* p1 = (const unsigned short*)&q1;
            #pragma unroll
            for (int c = 0; c < 8; ++c) { qr[c] = b2f(p0[c]); qr[8 + c] = b2f(p1[c]); }
        }
        float sc[8];
        #pragma unroll
        for (int j = 0; j < 8; ++j) {
            uint4 k0 = *(const uint4*)&KVs[(j * 8 + ss) * 256 + h * 16];
            uint4 k1 = *(const uint4*)&KVs[(j * 8 + ss) * 256 + h * 16 + 8];
            const unsigned short* kp0 = (const unsigned short*)&k0;
            const unsigned short* kp1 = (const unsigned short*)&k1;
            float s = 0.0f;
            #pragma unroll
            for (int c = 0; c < 8; ++c) {
                s = fmaf(qr[c], b2f(kp0[c]), s);
                s = fmaf(qr[8 + c], b2f(kp1[c]), s);
            }
            sc[j] = s * 0.25f;
        }
        float mx = -1e30f;
        #pragma unroll
        for (int j = 0; j < 8; ++j) mx = fmaxf(mx, sc[j]);
        float pe[8], se = 0.0f;
        #pragma unroll
        for (int j = 0; j < 8; ++j) { pe[j] = __expf(sc[j] - mx); se += pe[j]; }
        float inv = 1.0f / se;
        float o[16] = {};
        #pragma unroll
        for (int j = 0; j < 8; ++j) {
            uint4 v0 = *(const uint4*)&KVs[(j * 8 + ss) * 256 + 128 + h * 16];
            uint4 v1 = *(const uint4*)&KVs[(j * 8 + ss) * 256 + 128 + h * 16 + 8];
            const unsigned short* vp0 = (const unsigned short*)&v0;
            const unsigned short* vp1 = (const unsigned short*)&v1;
            #pragma unroll
            for (int c = 0; c < 8; ++c) {
                o[c]     += pe[j] * b2f(vp0[c]);
                o[8 + c] += pe[j] * b2f(vp1[c]);
            }
        }
        ushort4 w0 = (ushort4){f2b(o[0]*inv),  f2b(o[1]*inv),  f2b(o[2]*inv),  f2b(o[3]*inv)};
        ushort4 w1 = (ushort4){f2b(o[4]*inv),  f2b(o[5]*inv),  f2b(o[6]*inv),  f2b(o[7]*inv)};
        ushort4 w2 = (ushort4){f2b(o[8]*inv),  f2b(o[9]*inv),  f2b(o[10]*inv), f2b(o[11]*inv)};
        ushort4 w3 = (ushort4){f2b(o[12]*inv), f2b(o[13]*inv), f2b(o[14]*inv), f2b(o[15]*inv)};
        *(ushort4*)&Qs[rq * 136 + h * 16]      = w0;
        *(ushort4*)&Qs[rq * 136 + h * 16 + 4]  = w1;
        *(ushort4*)&Qs[rq * 136 + h * 16 + 8]  = w2;
        *(ushort4*)&Qs[rq * 136 + h * 16 + 12] = w3;
    }
    __syncthreads();

    f32x4 acc[2][4] = {};
    #pragma unroll
    for (int kf = 0; kf < 4; ++kf) {
        bf16x8 a[2], b[4];
        #pragma unroll
        for (int fm = 0; fm < 2; ++fm)
            a[fm] = *(const bf16x8*)&Qs[(wm + fm * 16 + ln) * 136 + kf * 32 + q * 8];
        #pragma unroll
        for (int fn = 0; fn < 4; ++fn)
            b[fn] = ldg_f32_b8(Wio + (size_t)(wn + fn * 16 + ln) * 128 + kf * 32 + q * 8);
        #pragma unroll
        for (int fm = 0; fm < 2; ++fm)
            #pragma unroll
            for (int fn = 0; fn < 4; ++fn)
                acc[fm][fn] = __builtin_amdgcn_mfma_f32_16x16x32_bf16(a[fm], b[fn], acc[fm][fn], 0, 0, 0);
    }
    #pragma unroll
    for (int fm = 0; fm < 2; ++fm)
        #pragma unroll
        for (int r = 0; r < 4; ++r) {
            int rl = wm + fm * 16 + q * 4 + r;
            size_t g = (size_t)(rl >> 3) * 2048 + s0 + (rl & 7);
            float sc = sim[g];
            #pragma unroll
            for (int fn = 0; fn < 4; ++fn) {
                int col = wn + fn * 16 + ln;
                out[g * 128 + col] = (acc[fm][fn][r] + b_io[col]) * sc + x2[g * 128 + col];
            }
        }
}

// ---------------------------------------------------------------------------
extern "C" void kernel_launch(void* const* d_in, const int* in_sizes, int n_in,
                              void* d_out, int out_size, void* d_ws, size_t ws_size,
                              hipStream_t stream)
{
    const float* x        = (const float*)d_in[0];
    const float* spatial  = (const float*)d_in[1];
    const float* temporal = (const float*)d_in[2];
    const float* lw_in_w  = (const float*)d_in[3];
    const float* lw_in_b  = (const float*)d_in[4];
    const float* lw_out_w = (const float*)d_in[5];
    const float* lw_out_b = (const float*)d_in[6];
    const float* spat_w   = (const float*)d_in[7];
    const float* spat_b   = (const float*)d_in[8];
    const float* temp_w   = (const float*)d_in[9];
    const float* temp_b   = (const float*)d_in[10];
    const float* int_in_w = (const float*)d_in[11];
    const float* int_in_b = (const float*)d_in[12];
    const float* int_out_w= (const float*)d_in[13];
    const float* int_out_b= (const float*)d_in[14];
    const float* ffn_w1   = (const float*)d_in[15];
    const float* ffn_b1   = (const float*)d_in[16];
    const float* ffn_w2   = (const float*)d_in[17];
    const float* ffn_b2   = (const float*)d_in[18];
    const float* ln1_g    = (const float*)d_in[19];
    const float* ln1_b    = (const float*)d_in[20];
    const float* ln2_g    = (const float*)d_in[21];
    const float* ln2_b    = (const float*)d_in[22];
    float* out = (float*)d_out;

    // ---- workspace layout (bytes) ----
    char* base = (char*)d_ws;
    float*          x1   = (float*)(base + 0);            // 8,388,608 (alias part)
    unsigned short* x1b  = (unsigned short*)(base + 8388608);    // 4,194,304
    float*          x2   = (float*)(base + 12582912);     // 8,388,608
    unsigned short* snb  = (unsigned short*)(base + 20971520);   // 4,194,304
    unsigned short* tnb  = (unsigned short*)(base + 25165824);   // 4,194,304
    unsigned short* seb  = (unsigned short*)(base + 29360128);   // 4,194,304
    unsigned short* teb  = (unsigned short*)(base + 33554432);   // 4,194,304
    unsigned short* Mtb  = (unsigned short*)(base + 37748736);   //   262,144
    float*          simb = (float*)(base + 38010880);     //    65,536
    unsigned short* Wb   = (unsigned short*)(base + 38076416);   //   262,144
    float*          part = x1;   // x1 dead after phaseB; atb runs later

    // A: win_block (256) + convW for ffn weights (512)
    phaseA<<<768, 256, 0, stream>>>(
        x, lw_in_w, lw_in_b, lw_out_w, lw_out_b, ln1_g, ln1_b, x1, x1b,
        ffn_w1, ffn_w2, Wb);
    // B: ffn barrier-free (256) + stproj barrier-free (512)
    phaseB<<<768, 256, 0, stream>>>(
        x1b, x1, Wb, ffn_b1, ffn_b2, ln2_g, ln2_b, x2,
        spatial, temporal, spat_w, temp_w, spat_b, temp_b,
        snb, tnb, seb, teb);
    // C: M_b split-K (bf16 in, fp32 acc)
    atb_split_kernel<<<dim3(2, 2, 8 * ATB_SPLIT), 256, 0, stream>>>(snb, tnb, part);
    // D: reduce + transpose -> bf16 M^T
    atb_reduce_kernel<<<512, 256, 0, stream>>>(part, Mtb);
    // E: sim via MFMA
    simgemm_kernel<<<256, 256, 0, stream>>>(snb, tnb, Mtb, simb);
    // F: interaction block
    inter_block<<<2048 / 8, 256, 0, stream>>>(
        seb, teb, int_in_w, int_in_b, int_out_w, int_out_b, simb, x2, out);
}

// Round 10
// 249.347 us; speedup vs baseline: 1.1507x; 1.1507x over previous
//
#include <hip/hip_runtime.h>
#include <math.h>

#define BB 8
#define SS 2048
#define NTOK (BB * SS)   // 16384
#define ATB_SPLIT 16

using bf16x8 = __attribute__((ext_vector_type(8))) short;
using f32x4  = __attribute__((ext_vector_type(4))) float;

__device__ __forceinline__ float gelu_tanh(float x) {
    float y = 0.7978845608f * (x + 0.044715f * x * x * x);
    float e = __expf(2.0f * y);
    float t = 1.0f - 2.0f / (e + 1.0f);
    return 0.5f * x * (1.0f + t);
}
__device__ __forceinline__ unsigned short f2b(float f) {
    unsigned int u = __float_as_uint(f);
    u += 0x7FFFu + ((u >> 16) & 1u);
    return (unsigned short)(u >> 16);
}
__device__ __forceinline__ float b2f(unsigned short u) {
    return __uint_as_float((unsigned int)u << 16);
}
__device__ __forceinline__ bf16x8 ldg_f32_b8(const float* p) {
    float4 f0 = *(const float4*)p, f1 = *(const float4*)(p + 4);
    union { ushort4 u[2]; bf16x8 v; } r;
    r.u[0] = (ushort4){f2b(f0.x), f2b(f0.y), f2b(f0.z), f2b(f0.w)};
    r.u[1] = (ushort4){f2b(f1.x), f2b(f1.y), f2b(f1.z), f2b(f1.w)};
    return r.v;
}

// ---------------------------------------------------------------------------
// Phase A: bx<256 -> fused window block (self-converting weights);
//          bx>=256 -> convert ffn weights fp32->bf16 into Wb.
// ---------------------------------------------------------------------------
__global__ __launch_bounds__(256) void phaseA(
    const float* __restrict__ x,
    const float* __restrict__ lw_in_w, const float* __restrict__ b_in,
    const float* __restrict__ lw_out_w, const float* __restrict__ b_out,
    const float* __restrict__ lng, const float* __restrict__ lnb,
    float* __restrict__ x1, unsigned short* __restrict__ x1b,
    const float* __restrict__ ffn_w1, const float* __restrict__ ffn_w2,
    unsigned short* __restrict__ Wb)
{
    __shared__ unsigned short Qs[64 * 136];   // Q; attn-out in-place
    __shared__ unsigned short Ks[64 * 136];
    __shared__ unsigned short Vt[128 * 72];
    __shared__ unsigned short Pb[4][32 * 72];
    __shared__ float red[2][64][2];
    const int tid = threadIdx.x;

    if (blockIdx.x >= 256) {   // ---- convW role ----
        int i = (blockIdx.x - 256) * 256 + tid;   // 0..131071
        float v = (i < 65536) ? ffn_w1[i] : ffn_w2[i - 65536];
        Wb[i] = f2b(v);
        return;
    }

    const int m0 = blockIdx.x * 64;
    const int wv = tid >> 6, lane = tid & 63, ln = lane & 15, q = lane >> 4;
    const int wm = (wv >> 1) * 32, wn = (wv & 1) * 64;

    bf16x8 afr[4][2];
    #pragma unroll
    for (int kf = 0; kf < 4; ++kf)
        #pragma unroll
        for (int fm = 0; fm < 2; ++fm)
            afr[kf][fm] = ldg_f32_b8(x + (size_t)(m0 + wm + fm * 16 + ln) * 128 + kf * 32 + q * 8);

    #pragma unroll
    for (int p = 0; p < 3; ++p) {
        f32x4 acc[2][4] = {};
        #pragma unroll
        for (int kf = 0; kf < 4; ++kf) {
            bf16x8 b[4];
            #pragma unroll
            for (int fn = 0; fn < 4; ++fn)
                b[fn] = ldg_f32_b8(lw_in_w + (size_t)(p * 128 + wn + fn * 16 + ln) * 128 + kf * 32 + q * 8);
            #pragma unroll
            for (int fm = 0; fm < 2; ++fm)
                #pragma unroll
                for (int fn = 0; fn < 4; ++fn)
                    acc[fm][fn] = __builtin_amdgcn_mfma_f32_16x16x32_bf16(afr[kf][fm], b[fn], acc[fm][fn], 0, 0, 0);
        }
        #pragma unroll
        for (int fm = 0; fm < 2; ++fm)
            #pragma unroll
            for (int r = 0; r < 4; ++r) {
                int rl = wm + fm * 16 + q * 4 + r;
                #pragma unroll
                for (int fn = 0; fn < 4; ++fn) {
                    int col = wn + fn * 16 + ln;
                    unsigned short v = f2b(acc[fm][fn][r] + b_in[p * 128 + col]);
                    if (p == 0)      Qs[rl * 136 + col] = v;
                    else if (p == 1) Ks[rl * 136 + col] = v;
                    else             Vt[col * 72 + rl] = v;
                }
            }
    }
    __syncthreads();

    // ---- MFMA attention: wave = (m-half mh, head-quad hq) ----
    {
        const int mh = wv >> 1, hq = wv & 1;
        unsigned short* P = &Pb[wv][0];
        #pragma unroll
        for (int hh = 0; hh < 4; ++hh) {
            const int h = hq * 4 + hh;
            f32x4 sacc[2][4] = {};
            bf16x8 az[2] = {}, bz[4] = {};
            if (q < 2) {
                #pragma unroll
                for (int fm = 0; fm < 2; ++fm)
                    az[fm] = *(const bf16x8*)&Qs[(mh * 32 + fm * 16 + ln) * 136 + h * 16 + q * 8];
                #pragma unroll
                for (int fn = 0; fn < 4; ++fn)
                    bz[fn] = *(const bf16x8*)&Ks[(fn * 16 + ln) * 136 + h * 16 + q * 8];
            }
            #pragma unroll
            for (int fm = 0; fm < 2; ++fm)
                #pragma unroll
                for (int fn = 0; fn < 4; ++fn)
                    sacc[fm][fn] = __builtin_amdgcn_mfma_f32_16x16x32_bf16(az[fm], bz[fn], sacc[fm][fn], 0, 0, 0);
            float invr[2][4];
            #pragma unroll
            for (int fm = 0; fm < 2; ++fm)
                #pragma unroll
                for (int r = 0; r < 4; ++r) {
                    int gi = mh * 32 + fm * 16 + q * 4 + r;
                    float mx = -1e30f;
                    #pragma unroll
                    for (int fn = 0; fn < 4; ++fn) {
                        int j = fn * 16 + ln;
                        float s = sacc[fm][fn][r] * 0.25f;
                        if (j > gi) s = -1e30f;
                        sacc[fm][fn][r] = s;
                        mx = fmaxf(mx, s);
                    }
                    #pragma unroll
                    for (int off = 1; off < 16; off <<= 1)
                        mx = fmaxf(mx, __shfl_xor(mx, off, 64));
                    float sum = 0.0f;
                    #pragma unroll
                    for (int fn = 0; fn < 4; ++fn) {
                        float p_ = __expf(sacc[fm][fn][r] - mx);
                        sacc[fm][fn][r] = p_;
                        sum += p_;
                    }
                    #pragma unroll
                    for (int off = 1; off < 16; off <<= 1)
                        sum += __shfl_xor(sum, off, 64);
                    invr[fm][r] = 1.0f / sum;
                    #pragma unroll
                    for (int fn = 0; fn < 4; ++fn)
                        P[(fm * 16 + q * 4 + r) * 72 + fn * 16 + ln] = f2b(sacc[fm][fn][r]);
                }
            f32x4 oacc[2] = {};
            #pragma unroll
            for (int kf2 = 0; kf2 < 2; ++kf2) {
                bf16x8 pa[2], vb;
                #pragma unroll
                for (int fm = 0; fm < 2; ++fm)
                    pa[fm] = *(const bf16x8*)&P[(fm * 16 + ln) * 72 + kf2 * 32 + q * 8];
                vb = *(const bf16x8*)&Vt[(h * 16 + ln) * 72 + kf2 * 32 + q * 8];
                #pragma unroll
                for (int fm = 0; fm < 2; ++fm)
                    oacc[fm] = __builtin_amdgcn_mfma_f32_16x16x32_bf16(pa[fm], vb, oacc[fm], 0, 0, 0);
            }
            #pragma unroll
            for (int fm = 0; fm < 2; ++fm)
                #pragma unroll
                for (int r = 0; r < 4; ++r)
                    Qs[(mh * 32 + fm * 16 + q * 4 + r) * 136 + h * 16 + ln] =
                        f2b(oacc[fm][r] * invr[fm][r]);
        }
    }
    __syncthreads();

    // ---- out-proj + residual(x) + LN1 ----
    f32x4 acc[2][4] = {};
    #pragma unroll
    for (int kf = 0; kf < 4; ++kf) {
        bf16x8 a[2], b[4];
        #pragma unroll
        for (int fm = 0; fm < 2; ++fm)
            a[fm] = *(const bf16x8*)&Qs[(wm + fm * 16 + ln) * 136 + kf * 32 + q * 8];
        #pragma unroll
        for (int fn = 0; fn < 4; ++fn)
            b[fn] = ldg_f32_b8(lw_out_w + (size_t)(wn + fn * 16 + ln) * 128 + kf * 32 + q * 8);
        #pragma unroll
        for (int fm = 0; fm < 2; ++fm)
            #pragma unroll
            for (int fn = 0; fn < 4; ++fn)
                acc[fm][fn] = __builtin_amdgcn_mfma_f32_16x16x32_bf16(a[fm], b[fn], acc[fm][fn], 0, 0, 0);
    }
    #pragma unroll
    for (int fm = 0; fm < 2; ++fm)
        #pragma unroll
        for (int r = 0; r < 4; ++r) {
            int rl = wm + fm * 16 + q * 4 + r;
            int row = m0 + rl;
            float s1 = 0.0f, s2 = 0.0f;
            #pragma unroll
            for (int fn = 0; fn < 4; ++fn) {
                int col = wn + fn * 16 + ln;
                float vv = acc[fm][fn][r] + b_out[col] + x[(size_t)row * 128 + col];
                acc[fm][fn][r] = vv;
                s1 += vv; s2 += vv * vv;
            }
            #pragma unroll
            for (int off = 1; off < 16; off <<= 1) {
                s1 += __shfl_xor(s1, off, 64);
                s2 += __shfl_xor(s2, off, 64);
            }
            if (ln == 0) { red[0][rl][wv & 1] = s1; red[1][rl][wv & 1] = s2; }
        }
    __syncthreads();
    #pragma unroll
    for (int fm = 0; fm < 2; ++fm)
        #pragma unroll
        for (int r = 0; r < 4; ++r) {
            int rl = wm + fm * 16 + q * 4 + r;
            int row = m0 + rl;
            float mu = (red[0][rl][0] + red[0][rl][1]) * (1.0f / 128.0f);
            float var = (red[1][rl][0] + red[1][rl][1]) * (1.0f / 128.0f) - mu * mu;
            float rs = rsqrtf(var + 1e-5f);
            #pragma unroll
            for (int fn = 0; fn < 4; ++fn) {
                int col = wn + fn * 16 + ln;
                float o = (acc[fm][fn][r] - mu) * rs * lng[col] + lnb[col];
                x1[(size_t)row * 128 + col] = o;
                x1b[(size_t)row * 128 + col] = f2b(o);
            }
        }
}

// ---------------------------------------------------------------------------
// Fused FFN (R7 structure + double-buffered Hs -> 8 barriers/block).
// 64-token blocks, grid 256. W-frags direct from global bf16.
// ---------------------------------------------------------------------------
__global__ __launch_bounds__(256) void ffn_fused(
    const unsigned short* __restrict__ x1b, const float* __restrict__ x1,
    const unsigned short* __restrict__ w1, const unsigned short* __restrict__ w2,
    const float* __restrict__ b1, const float* __restrict__ b2,
    const float* __restrict__ lng, const float* __restrict__ lnb,
    float* __restrict__ x2)
{
    __shared__ unsigned short Xs[64 * 136];
    __shared__ unsigned short Hs[2][64 * 72];
    __shared__ float red[2][64][2];
    const int tid = threadIdx.x, t0 = blockIdx.x * 64;
    const int wv = tid >> 6, lane = tid & 63, ln = lane & 15, q = lane >> 4;
    const int wm = (wv >> 1) * 32;
    const int wn1 = (wv & 1) * 32, wn2 = (wv & 1) * 64;

    const uint4* X4 = (const uint4*)(x1b + (size_t)t0 * 128);
    #pragma unroll
    for (int t = 0; t < 4; ++t) {
        int idx = tid + t * 256;
        int r = idx >> 4, c = idx & 15;
        *(uint4*)&Xs[r * 136 + c * 8] = X4[r * 16 + c];
    }
    __syncthreads();

    bf16x8 xfr[4][2];
    #pragma unroll
    for (int kf = 0; kf < 4; ++kf)
        #pragma unroll
        for (int fm = 0; fm < 2; ++fm)
            xfr[kf][fm] = *(const bf16x8*)&Xs[(wm + fm * 16 + ln) * 136 + kf * 32 + q * 8];

    f32x4 acc2[2][4] = {};
    for (int ch = 0; ch < 8; ++ch) {
        const int hc0 = ch * 64;
        unsigned short* Hb = &Hs[ch & 1][0];
        f32x4 acc1[2][2] = {};
        #pragma unroll
        for (int kf = 0; kf < 4; ++kf) {
            bf16x8 b[2];
            #pragma unroll
            for (int fn = 0; fn < 2; ++fn)
                b[fn] = *(const bf16x8*)&w1[(size_t)(hc0 + wn1 + fn * 16 + ln) * 128 + kf * 32 + q * 8];
            #pragma unroll
            for (int fm = 0; fm < 2; ++fm)
                #pragma unroll
                for (int fn = 0; fn < 2; ++fn)
                    acc1[fm][fn] = __builtin_amdgcn_mfma_f32_16x16x32_bf16(xfr[kf][fm], b[fn], acc1[fm][fn], 0, 0, 0);
        }
        #pragma unroll
        for (int fm = 0; fm < 2; ++fm)
            #pragma unroll
            for (int fn = 0; fn < 2; ++fn)
                #pragma unroll
                for (int r = 0; r < 4; ++r) {
                    int rl = wm + fm * 16 + q * 4 + r;
                    int col = wn1 + fn * 16 + ln;
                    Hb[rl * 72 + col] = f2b(gelu_tanh(acc1[fm][fn][r] + b1[hc0 + col]));
                }
        __syncthreads();
        #pragma unroll
        for (int kf2 = 0; kf2 < 2; ++kf2) {
            bf16x8 a[2], b[4];
            #pragma unroll
            for (int fm = 0; fm < 2; ++fm)
                a[fm] = *(const bf16x8*)&Hb[(wm + fm * 16 + ln) * 72 + kf2 * 32 + q * 8];
            #pragma unroll
            for (int fn = 0; fn < 4; ++fn)
                b[fn] = *(const bf16x8*)&w2[(size_t)(wn2 + fn * 16 + ln) * 512 + hc0 + kf2 * 32 + q * 8];
            #pragma unroll
            for (int fm = 0; fm < 2; ++fm)
                #pragma unroll
                for (int fn = 0; fn < 4; ++fn)
                    acc2[fm][fn] = __builtin_amdgcn_mfma_f32_16x16x32_bf16(a[fm], b[fn], acc2[fm][fn], 0, 0, 0);
        }
        // no second barrier: next chunk writes the other Hs buffer
    }
    #pragma unroll
    for (int fm = 0; fm < 2; ++fm)
        #pragma unroll
        for (int r = 0; r < 4; ++r) {
            int rl = wm + fm * 16 + q * 4 + r;
            int row = t0 + rl;
            float s1 = 0.0f, s2 = 0.0f;
            #pragma unroll
            for (int fn = 0; fn < 4; ++fn) {
                int col = wn2 + fn * 16 + ln;
                float vv = acc2[fm][fn][r] + b2[col] + x1[(size_t)row * 128 + col];
                acc2[fm][fn][r] = vv;
                s1 += vv; s2 += vv * vv;
            }
            #pragma unroll
            for (int off = 1; off < 16; off <<= 1) {
                s1 += __shfl_xor(s1, off, 64);
                s2 += __shfl_xor(s2, off, 64);
            }
            if (ln == 0) { red[0][rl][wv & 1] = s1; red[1][rl][wv & 1] = s2; }
        }
    __syncthreads();
    #pragma unroll
    for (int fm = 0; fm < 2; ++fm)
        #pragma unroll
        for (int r = 0; r < 4; ++r) {
            int rl = wm + fm * 16 + q * 4 + r;
            int row = t0 + rl;
            float mu = (red[0][rl][0] + red[0][rl][1]) * (1.0f / 128.0f);
            float var = (red[1][rl][0] + red[1][rl][1]) * (1.0f / 128.0f) - mu * mu;
            float rs = rsqrtf(var + 1e-5f);
            #pragma unroll
            for (int fn = 0; fn < 4; ++fn) {
                int col = wn2 + fn * 16 + ln;
                x2[(size_t)row * 128 + col] = (acc2[fm][fn][r] - mu) * rs * lng[col] + lnb[col];
            }
        }
}

// ---------------------------------------------------------------------------
// se/te projection + cosine norm, grid (256,2); bf16 outputs only.
// ---------------------------------------------------------------------------
__global__ __launch_bounds__(256) void stproj_kernel(
    const float* __restrict__ sp, const float* __restrict__ tp,
    const float* __restrict__ Wsp, const float* __restrict__ Wtp,
    const float* __restrict__ bsp, const float* __restrict__ btp,
    unsigned short* __restrict__ snb, unsigned short* __restrict__ tnb,
    unsigned short* __restrict__ seb, unsigned short* __restrict__ teb)
{
    __shared__ float red[64][2];
    const int tid = threadIdx.x, m0 = blockIdx.x * 64, y = blockIdx.y;
    const float* Af = y ? tp : sp;
    const float* Wf = y ? Wtp : Wsp;
    const float* bias = y ? btp : bsp;
    unsigned short* nb = y ? tnb : snb;
    unsigned short* raw = y ? teb : seb;
    const int wv = tid >> 6, lane = tid & 63, ln = lane & 15, q = lane >> 4;
    const int wm = (wv >> 1) * 32, wn = (wv & 1) * 64;

    f32x4 acc[2][4] = {};
    #pragma unroll
    for (int kf = 0; kf < 4; ++kf) {
        bf16x8 a[2], b[4];
        #pragma unroll
        for (int fm = 0; fm < 2; ++fm)
            a[fm] = ldg_f32_b8(Af + (size_t)(m0 + wm + fm * 16 + ln) * 128 + kf * 32 + q * 8);
        #pragma unroll
        for (int fn = 0; fn < 4; ++fn)
            b[fn] = ldg_f32_b8(Wf + (size_t)(wn + fn * 16 + ln) * 128 + kf * 32 + q * 8);
        #pragma unroll
        for (int fm = 0; fm < 2; ++fm)
            #pragma unroll
            for (int fn = 0; fn < 4; ++fn)
                acc[fm][fn] = __builtin_amdgcn_mfma_f32_16x16x32_bf16(a[fm], b[fn], acc[fm][fn], 0, 0, 0);
    }
    #pragma unroll
    for (int fm = 0; fm < 2; ++fm)
        #pragma unroll
        for (int r = 0; r < 4; ++r) {
            int rl = wm + fm * 16 + q * 4 + r;
            float s2 = 0.0f;
            #pragma unroll
            for (int fn = 0; fn < 4; ++fn) {
                int col = wn + fn * 16 + ln;
                float vv = acc[fm][fn][r] + bias[col];
                acc[fm][fn][r] = vv;
                s2 += vv * vv;
            }
            #pragma unroll
            for (int off = 1; off < 16; off <<= 1) s2 += __shfl_xor(s2, off, 64);
            if (ln == 0) red[rl][wv & 1] = s2;
        }
    __syncthreads();
    #pragma unroll
    for (int fm = 0; fm < 2; ++fm)
        #pragma unroll
        for (int r = 0; r < 4; ++r) {
            int rl = wm + fm * 16 + q * 4 + r;
            int row = m0 + rl;
            float inv = 1.0f / fmaxf(sqrtf(red[rl][0] + red[rl][1]), 1e-8f);
            #pragma unroll
            for (int fn = 0; fn < 4; ++fn) {
                int col = wn + fn * 16 + ln;
                float vv = acc[fm][fn][r];
                nb[(size_t)row * 128 + col] = f2b(vv * inv);
                raw[(size_t)row * 128 + col] = f2b(vv);
            }
        }
}

// ---------------------------------------------------------------------------
// Split-K A^T B per batch, bf16 in / fp32 accumulate.
// ---------------------------------------------------------------------------
__global__ __launch_bounds__(256) void atb_split_kernel(
    const unsigned short* __restrict__ snb, const unsigned short* __restrict__ tnb,
    float* __restrict__ part)
{
    const int b = blockIdx.z / ATB_SPLIT;
    const int chunk = blockIdx.z % ATB_SPLIT;
    const int d0 = blockIdx.x * 64, e0 = blockIdx.y * 64;
    __shared__ float Ss[32][68];
    __shared__ float Ts[32][68];
    const int tid = threadIdx.x;
    const int tx = tid % 16, ty = tid / 16;
    const int jbase = chunk * (SS / ATB_SPLIT);
    float acc[4][4] = {};
    for (int j0 = jbase; j0 < jbase + SS / ATB_SPLIT; j0 += 32) {
        {
            int r = tid >> 3, c8 = (tid & 7) * 8;
            uint4 sv = *(const uint4*)&snb[(size_t)(b * SS + j0 + r) * 128 + d0 + c8];
            uint4 tv = *(const uint4*)&tnb[(size_t)(b * SS + j0 + r) * 128 + e0 + c8];
            const unsigned short* sp = (const unsigned short*)&sv;
            const unsigned short* tp = (const unsigned short*)&tv;
            #pragma unroll
            for (int c = 0; c < 8; ++c) {
                Ss[r][c8 + c] = b2f(sp[c]);
                Ts[r][c8 + c] = b2f(tp[c]);
            }
        }
        __syncthreads();
        #pragma unroll
        for (int kk = 0; kk < 32; ++kk) {
            float4 af = *(const float4*)&Ss[kk][ty * 4];
            float4 wf = *(const float4*)&Ts[kk][tx * 4];
            float a[4] = {af.x, af.y, af.z, af.w};
            float w[4] = {wf.x, wf.y, wf.z, wf.w};
            #pragma unroll
            for (int i = 0; i < 4; ++i)
                #pragma unroll
                for (int j = 0; j < 4; ++j)
                    acc[i][j] = fmaf(a[i], w[j], acc[i][j]);
        }
        __syncthreads();
    }
    float* pp = part + (size_t)(b * ATB_SPLIT + chunk) * 16384;
    #pragma unroll
    for (int i = 0; i < 4; ++i) {
        float4 ov = {acc[i][0], acc[i][1], acc[i][2], acc[i][3]};
        *(float4*)&pp[(size_t)(d0 + ty * 4 + i) * 128 + e0 + tx * 4] = ov;
    }
}

// Mtb[b][e*128+d] = bf16( sum_chunk part[(b*16+c)*16384 + d*128 + e] )
__global__ __launch_bounds__(256) void atb_reduce_kernel(
    const float* __restrict__ part, unsigned short* __restrict__ Mtb)
{
    int i = blockIdx.x * 256 + threadIdx.x;   // 0..131071
    int b = i >> 14, rem = i & 16383;
    int e = rem >> 7, d = rem & 127;
    const float* pp = part + (size_t)b * ATB_SPLIT * 16384 + (size_t)d * 128 + e;
    float s = 0.0f;
    #pragma unroll
    for (int c = 0; c < ATB_SPLIT; ++c) s += pp[(size_t)c * 16384];
    Mtb[i] = f2b(s);
}

// ---------------------------------------------------------------------------
// sim[row] = (1/S) <snb@M_b, tnb>_row via MFMA; frags direct from global.
// ---------------------------------------------------------------------------
__global__ __launch_bounds__(256) void simgemm_kernel(
    const unsigned short* __restrict__ snb, const unsigned short* __restrict__ tnb,
    const unsigned short* __restrict__ Mtb, float* __restrict__ sim)
{
    __shared__ float red[64][2];
    const int tid = threadIdx.x, m0 = blockIdx.x * 64, b = m0 >> 11;
    const int wv = tid >> 6, lane = tid & 63, ln = lane & 15, q = lane >> 4;
    const int wm = (wv >> 1) * 32, wn = (wv & 1) * 64;

    f32x4 acc[2][4] = {};
    #pragma unroll
    for (int kf = 0; kf < 4; ++kf) {
        bf16x8 a[2], bb[4];
        #pragma unroll
        for (int fm = 0; fm < 2; ++fm)
            a[fm] = *(const bf16x8*)&snb[(size_t)(m0 + wm + fm * 16 + ln) * 128 + kf * 32 + q * 8];
        #pragma unroll
        for (int fn = 0; fn < 4; ++fn)
            bb[fn] = *(const bf16x8*)&Mtb[(size_t)b * 16384 + (size_t)(wn + fn * 16 + ln) * 128 + kf * 32 + q * 8];
        #pragma unroll
        for (int fm = 0; fm < 2; ++fm)
            #pragma unroll
            for (int fn = 0; fn < 4; ++fn)
                acc[fm][fn] = __builtin_amdgcn_mfma_f32_16x16x32_bf16(a[fm], bb[fn], acc[fm][fn], 0, 0, 0);
    }
    #pragma unroll
    for (int fm = 0; fm < 2; ++fm)
        #pragma unroll
        for (int r = 0; r < 4; ++r) {
            int rl = wm + fm * 16 + q * 4 + r;
            int row = m0 + rl;
            float s = 0.0f;
            #pragma unroll
            for (int fn = 0; fn < 4; ++fn) {
                int col = wn + fn * 16 + ln;
                s += acc[fm][fn][r] * b2f(tnb[(size_t)row * 128 + col]);
            }
            #pragma unroll
            for (int off = 1; off < 16; off <<= 1) s += __shfl_xor(s, off, 64);
            if (ln == 0) red[rl][wv & 1] = s;
        }
    __syncthreads();
    if (tid < 64) sim[m0 + tid] = (red[tid][0] + red[tid][1]) * (1.0f / (float)SS);
}

// ---------------------------------------------------------------------------
// Fused interaction block (self-converting weights).
// ---------------------------------------------------------------------------
__global__ __launch_bounds__(256) void inter_block(
    const unsigned short* __restrict__ seb, const unsigned short* __restrict__ teb,
    const float* __restrict__ Wint,  // (384,128) fp32
    const float* __restrict__ b_int,
    const float* __restrict__ Wio,   // (128,128) fp32
    const float* __restrict__ b_io,
    const float* __restrict__ sim, const float* __restrict__ x2,
    float* __restrict__ out)
{
    __shared__ unsigned short Qs[64 * 136];
    __shared__ unsigned short KVs[64 * 256];
    const int tid = threadIdx.x, s0 = blockIdx.x * 8;
    const int wv = tid >> 6, lane = tid & 63, ln = lane & 15, q = lane >> 4;
    const int wm = (wv >> 1) * 32, wn = (wv & 1) * 64;

    bf16x8 afr[4][2];
    #pragma unroll
    for (int kf = 0; kf < 4; ++kf)
        #pragma unroll
        for (int fm = 0; fm < 2; ++fm) {
            int rl = wm + fm * 16 + ln;
            size_t g = (size_t)(rl >> 3) * 2048 + s0 + (rl & 7);
            afr[kf][fm] = *(const bf16x8*)&seb[g * 128 + kf * 32 + q * 8];
        }

    #pragma unroll
    for (int p = 0; p < 3; ++p) {
        if (p == 1) {
            #pragma unroll
            for (int kf = 0; kf < 4; ++kf)
                #pragma unroll
                for (int fm = 0; fm < 2; ++fm) {
                    int rl = wm + fm * 16 + ln;
                    size_t g = (size_t)(rl >> 3) * 2048 + s0 + (rl & 7);
                    afr[kf][fm] = *(const bf16x8*)&teb[g * 128 + kf * 32 + q * 8];
                }
        }
        f32x4 acc[2][4] = {};
        #pragma unroll
        for (int kf = 0; kf < 4; ++kf) {
            bf16x8 b[4];
            #pragma unroll
            for (int fn = 0; fn < 4; ++fn)
                b[fn] = ldg_f32_b8(Wint + (size_t)(p * 128 + wn + fn * 16 + ln) * 128 + kf * 32 + q * 8);
            #pragma unroll
            for (int fm = 0; fm < 2; ++fm)
                #pragma unroll
                for (int fn = 0; fn < 4; ++fn)
                    acc[fm][fn] = __builtin_amdgcn_mfma_f32_16x16x32_bf16(afr[kf][fm], b[fn], acc[fm][fn], 0, 0, 0);
        }
        #pragma unroll
        for (int fm = 0; fm < 2; ++fm)
            #pragma unroll
            for (int r = 0; r < 4; ++r) {
                int rl = wm + fm * 16 + q * 4 + r;
                #pragma unroll
                for (int fn = 0; fn < 4; ++fn) {
                    int col = wn + fn * 16 + ln;
                    unsigned short v = f2b(acc[fm][fn][r] + b_int[p * 128 + col]);
                    if (p == 0) Qs[rl * 136 + col] = v;
                    else        KVs[rl * 256 + (p - 1) * 128 + col] = v;
                }
            }
        __syncthreads();
    }

    #pragma unroll
    for (int tt = 0; tt < 2; ++tt) {
        int task = tid + tt * 256;
        int ss = task >> 6, h = (task >> 3) & 7, i = task & 7;
        int rq = i * 8 + ss;
        float qr[16];
        {
            uint4 q0 = *(const uint4*)&Qs[rq * 136 + h * 16];
            uint4 q1 = *(const uint4*)&Qs[rq * 136 + h * 16 + 8];
            const unsigned short* p0 = (const unsigned short*)&q0;
            const unsigned short* p1 = (const unsigned short*)&q1;
            #pragma unroll
            for (int c = 0; c < 8; ++c) { qr[c] = b2f(p0[c]); qr[8 + c] = b2f(p1[c]); }
        }
        float sc[8];
        #pragma unroll
        for (int j = 0; j < 8; ++j) {
            uint4 k0 = *(const uint4*)&KVs[(j * 8 + ss) * 256 + h * 16];
            uint4 k1 = *(const uint4*)&KVs[(j * 8 + ss) * 256 + h * 16 + 8];
            const unsigned short* kp0 = (const unsigned short*)&k0;
            const unsigned short* kp1 = (const unsigned short*)&k1;
            float s = 0.0f;
            #pragma unroll
            for (int c = 0; c < 8; ++c) {
                s = fmaf(qr[c], b2f(kp0[c]), s);
                s = fmaf(qr[8 + c], b2f(kp1[c]), s);
            }
            sc[j] = s * 0.25f;
        }
        float mx = -1e30f;
        #pragma unroll
        for (int j = 0; j < 8; ++j) mx = fmaxf(mx, sc[j]);
        float pe[8], se = 0.0f;
        #pragma unroll
        for (int j = 0; j < 8; ++j) { pe[j] = __expf(sc[j] - mx); se += pe[j]; }
        float inv = 1.0f / se;
        float o[16] = {};
        #pragma unroll
        for (int j = 0; j < 8; ++j) {
            uint4 v0 = *(const uint4*)&KVs[(j * 8 + ss) * 256 + 128 + h * 16];
            uint4 v1 = *(const uint4*)&KVs[(j * 8 + ss) * 256 + 128 + h * 16 + 8];
            const unsigned short* vp0 = (const unsigned short*)&v0;
            const unsigned short* vp1 = (const unsigned short*)&v1;
            #pragma unroll
            for (int c = 0; c < 8; ++c) {
                o[c]     += pe[j] * b2f(vp0[c]);
                o[8 + c] += pe[j] * b2f(vp1[c]);
            }
        }
        ushort4 w0 = (ushort4){f2b(o[0]*inv),  f2b(o[1]*inv),  f2b(o[2]*inv),  f2b(o[3]*inv)};
        ushort4 w1 = (ushort4){f2b(o[4]*inv),  f2b(o[5]*inv),  f2b(o[6]*inv),  f2b(o[7]*inv)};
        ushort4 w2 = (ushort4){f2b(o[8]*inv),  f2b(o[9]*inv),  f2b(o[10]*inv), f2b(o[11]*inv)};
        ushort4 w3 = (ushort4){f2b(o[12]*inv), f2b(o[13]*inv), f2b(o[14]*inv), f2b(o[15]*inv)};
        *(ushort4*)&Qs[rq * 136 + h * 16]      = w0;
        *(ushort4*)&Qs[rq * 136 + h * 16 + 4]  = w1;
        *(ushort4*)&Qs[rq * 136 + h * 16 + 8]  = w2;
        *(ushort4*)&Qs[rq * 136 + h * 16 + 12] = w3;
    }
    __syncthreads();

    f32x4 acc[2][4] = {};
    #pragma unroll
    for (int kf = 0; kf < 4; ++kf) {
        bf16x8 a[2], b[4];
        #pragma unroll
        for (int fm = 0; fm < 2; ++fm)
            a[fm] = *(const bf16x8*)&Qs[(wm + fm * 16 + ln) * 136 + kf * 32 + q * 8];
        #pragma unroll
        for (int fn = 0; fn < 4; ++fn)
            b[fn] = ldg_f32_b8(Wio + (size_t)(wn + fn * 16 + ln) * 128 + kf * 32 + q * 8);
        #pragma unroll
        for (int fm = 0; fm < 2; ++fm)
            #pragma unroll
            for (int fn = 0; fn < 4; ++fn)
                acc[fm][fn] = __builtin_amdgcn_mfma_f32_16x16x32_bf16(a[fm], b[fn], acc[fm][fn], 0, 0, 0);
    }
    #pragma unroll
    for (int fm = 0; fm < 2; ++fm)
        #pragma unroll
        for (int r = 0; r < 4; ++r) {
            int rl = wm + fm * 16 + q * 4 + r;
            size_t g = (size_t)(rl >> 3) * 2048 + s0 + (rl & 7);
            float sc = sim[g];
            #pragma unroll
            for (int fn = 0; fn < 4; ++fn) {
                int col = wn + fn * 16 + ln;
                out[g * 128 + col] = (acc[fm][fn][r] + b_io[col]) * sc + x2[g * 128 + col];
            }
        }
}

// ---------------------------------------------------------------------------
extern "C" void kernel_launch(void* const* d_in, const int* in_sizes, int n_in,
                              void* d_out, int out_size, void* d_ws, size_t ws_size,
                              hipStream_t stream)
{
    const float* x        = (const float*)d_in[0];
    const float* spatial  = (const float*)d_in[1];
    const float* temporal = (const float*)d_in[2];
    const float* lw_in_w  = (const float*)d_in[3];
    const float* lw_in_b  = (const float*)d_in[4];
    const float* lw_out_w = (const float*)d_in[5];
    const float* lw_out_b = (const float*)d_in[6];
    const float* spat_w   = (const float*)d_in[7];
    const float* spat_b   = (const float*)d_in[8];
    const float* temp_w   = (const float*)d_in[9];
    const float* temp_b   = (const float*)d_in[10];
    const float* int_in_w = (const float*)d_in[11];
    const float* int_in_b = (const float*)d_in[12];
    const float* int_out_w= (const float*)d_in[13];
    const float* int_out_b= (const float*)d_in[14];
    const float* ffn_w1   = (const float*)d_in[15];
    const float* ffn_b1   = (const float*)d_in[16];
    const float* ffn_w2   = (const float*)d_in[17];
    const float* ffn_b2   = (const float*)d_in[18];
    const float* ln1_g    = (const float*)d_in[19];
    const float* ln1_b    = (const float*)d_in[20];
    const float* ln2_g    = (const float*)d_in[21];
    const float* ln2_b    = (const float*)d_in[22];
    float* out = (float*)d_out;

    // ---- workspace layout (bytes) ----
    char* base = (char*)d_ws;
    float*          x1   = (float*)(base + 0);            // 8,388,608 (alias part)
    unsigned short* x1b  = (unsigned short*)(base + 8388608);    // 4,194,304
    float*          x2   = (float*)(base + 12582912);     // 8,388,608
    unsigned short* snb  = (unsigned short*)(base + 20971520);   // 4,194,304
    unsigned short* tnb  = (unsigned short*)(base + 25165824);   // 4,194,304
    unsigned short* seb  = (unsigned short*)(base + 29360128);   // 4,194,304
    unsigned short* teb  = (unsigned short*)(base + 33554432);   // 4,194,304
    unsigned short* Mtb  = (unsigned short*)(base + 37748736);   //   262,144
    float*          simb = (float*)(base + 38010880);     //    65,536
    unsigned short* Wb   = (unsigned short*)(base + 38076416);   //   262,144
    float*          part = x1;   // x1 dead after ffn_fused; atb runs later

    // A: win_block (256) + convW for ffn weights (512)
    phaseA<<<768, 256, 0, stream>>>(
        x, lw_in_w, lw_in_b, lw_out_w, lw_out_b, ln1_g, ln1_b, x1, x1b,
        ffn_w1, ffn_w2, Wb);
    // B1: fused FFN + LN2 (double-buffered Hs)
    ffn_fused<<<256, 256, 0, stream>>>(
        x1b, x1, Wb, Wb + 65536, ffn_b1, ffn_b2, ln2_g, ln2_b, x2);
    // B2: se/te projections + cosine norm (bf16 outputs)
    stproj_kernel<<<dim3(256, 2), 256, 0, stream>>>(
        spatial, temporal, spat_w, temp_w, spat_b, temp_b,
        snb, tnb, seb, teb);
    // C: M_b split-K (bf16 in, fp32 acc)
    atb_split_kernel<<<dim3(2, 2, 8 * ATB_SPLIT), 256, 0, stream>>>(snb, tnb, part);
    // D: reduce + transpose -> bf16 M^T
    atb_reduce_kernel<<<512, 256, 0, stream>>>(part, Mtb);
    // E: sim via MFMA
    simgemm_kernel<<<256, 256, 0, stream>>>(snb, tnb, Mtb, simb);
    // F: interaction block
    inter_block<<<2048 / 8, 256, 0, stream>>>(
        seb, teb, int_in_w, int_in_b, int_out_w, int_out_b, simb, x2, out);
}

// Round 11
// 242.116 us; speedup vs baseline: 1.1850x; 1.0299x over previous
//
#include <hip/hip_runtime.h>
#include <math.h>

#define BB 8
#define SS 2048
#define NTOK (BB * SS)   // 16384
#define ATB_SPLIT 16

using bf16x8 = __attribute__((ext_vector_type(8))) short;
using f32x4  = __attribute__((ext_vector_type(4))) float;

__device__ __forceinline__ float gelu_tanh(float x) {
    float y = 0.7978845608f * (x + 0.044715f * x * x * x);
    float e = __expf(2.0f * y);
    float t = 1.0f - 2.0f / (e + 1.0f);
    return 0.5f * x * (1.0f + t);
}
__device__ __forceinline__ unsigned short f2b(float f) {
    unsigned int u = __float_as_uint(f);
    u += 0x7FFFu + ((u >> 16) & 1u);
    return (unsigned short)(u >> 16);
}
__device__ __forceinline__ float b2f(unsigned short u) {
    return __uint_as_float((unsigned int)u << 16);
}
__device__ __forceinline__ bf16x8 ldg_f32_b8(const float* p) {
    float4 f0 = *(const float4*)p, f1 = *(const float4*)(p + 4);
    union { ushort4 u[2]; bf16x8 v; } r;
    r.u[0] = (ushort4){f2b(f0.x), f2b(f0.y), f2b(f0.z), f2b(f0.w)};
    r.u[1] = (ushort4){f2b(f1.x), f2b(f1.y), f2b(f1.z), f2b(f1.w)};
    return r.v;
}

// ---------------------------------------------------------------------------
// Phase 1 (grid 1280): bx<256 win_block | bx<768 convW(ffn) | bx<1280 stproj.
// All three roles are mutually independent.
// ---------------------------------------------------------------------------
__global__ __launch_bounds__(256) void phase1(
    const float* __restrict__ x,
    const float* __restrict__ lw_in_w, const float* __restrict__ b_in,
    const float* __restrict__ lw_out_w, const float* __restrict__ b_out,
    const float* __restrict__ lng, const float* __restrict__ lnb,
    float* __restrict__ x1, unsigned short* __restrict__ x1b,
    const float* __restrict__ ffn_w1, const float* __restrict__ ffn_w2,
    unsigned short* __restrict__ Wb,
    const float* __restrict__ spatial, const float* __restrict__ temporal,
    const float* __restrict__ spat_w, const float* __restrict__ temp_w,
    const float* __restrict__ bsp, const float* __restrict__ btp,
    unsigned short* __restrict__ snb, unsigned short* __restrict__ tnb,
    unsigned short* __restrict__ seb, unsigned short* __restrict__ teb)
{
    __shared__ unsigned short Qs[64 * 136];   // Q; attn-out in-place
    __shared__ unsigned short Ks[64 * 136];
    __shared__ unsigned short Vt[128 * 72];
    __shared__ unsigned short Pb[4][32 * 72];
    __shared__ float red[2][64][2];
    const int tid = threadIdx.x;
    const int wv = tid >> 6, lane = tid & 63, ln = lane & 15, q = lane >> 4;

    if (blockIdx.x >= 768) {   // ---- stproj role ----
        const int idx2 = blockIdx.x - 768;        // 0..511
        const int y = idx2 >> 8;                  // 0 spatial, 1 temporal
        const int m0 = (idx2 & 255) * 64;
        const float* Af = y ? temporal : spatial;
        const float* Wf = y ? temp_w : spat_w;
        const float* bias = y ? btp : bsp;
        unsigned short* nb = y ? tnb : snb;
        unsigned short* raw = y ? teb : seb;
        const int wm = (wv >> 1) * 32, wn = (wv & 1) * 64;

        f32x4 acc[2][4] = {};
        #pragma unroll
        for (int kf = 0; kf < 4; ++kf) {
            bf16x8 a[2], b[4];
            #pragma unroll
            for (int fm = 0; fm < 2; ++fm)
                a[fm] = ldg_f32_b8(Af + (size_t)(m0 + wm + fm * 16 + ln) * 128 + kf * 32 + q * 8);
            #pragma unroll
            for (int fn = 0; fn < 4; ++fn)
                b[fn] = ldg_f32_b8(Wf + (size_t)(wn + fn * 16 + ln) * 128 + kf * 32 + q * 8);
            #pragma unroll
            for (int fm = 0; fm < 2; ++fm)
                #pragma unroll
                for (int fn = 0; fn < 4; ++fn)
                    acc[fm][fn] = __builtin_amdgcn_mfma_f32_16x16x32_bf16(a[fm], b[fn], acc[fm][fn], 0, 0, 0);
        }
        #pragma unroll
        for (int fm = 0; fm < 2; ++fm)
            #pragma unroll
            for (int r = 0; r < 4; ++r) {
                int rl = wm + fm * 16 + q * 4 + r;
                float s2 = 0.0f;
                #pragma unroll
                for (int fn = 0; fn < 4; ++fn) {
                    int col = wn + fn * 16 + ln;
                    float vv = acc[fm][fn][r] + bias[col];
                    acc[fm][fn][r] = vv;
                    s2 += vv * vv;
                }
                #pragma unroll
                for (int off = 1; off < 16; off <<= 1) s2 += __shfl_xor(s2, off, 64);
                if (ln == 0) red[0][rl][wv & 1] = s2;
            }
        __syncthreads();
        #pragma unroll
        for (int fm = 0; fm < 2; ++fm)
            #pragma unroll
            for (int r = 0; r < 4; ++r) {
                int rl = wm + fm * 16 + q * 4 + r;
                int row = m0 + rl;
                float inv = 1.0f / fmaxf(sqrtf(red[0][rl][0] + red[0][rl][1]), 1e-8f);
                #pragma unroll
                for (int fn = 0; fn < 4; ++fn) {
                    int col = wn + fn * 16 + ln;
                    float vv = acc[fm][fn][r];
                    nb[(size_t)row * 128 + col] = f2b(vv * inv);
                    raw[(size_t)row * 128 + col] = f2b(vv);
                }
            }
        return;
    }

    if (blockIdx.x >= 256) {   // ---- convW role ----
        int i = (blockIdx.x - 256) * 256 + tid;   // 0..131071
        float v = (i < 65536) ? ffn_w1[i] : ffn_w2[i - 65536];
        Wb[i] = f2b(v);
        return;
    }

    // ---- win_block role ----
    const int m0 = blockIdx.x * 64;
    const int wm = (wv >> 1) * 32, wn = (wv & 1) * 64;

    bf16x8 afr[4][2];
    #pragma unroll
    for (int kf = 0; kf < 4; ++kf)
        #pragma unroll
        for (int fm = 0; fm < 2; ++fm)
            afr[kf][fm] = ldg_f32_b8(x + (size_t)(m0 + wm + fm * 16 + ln) * 128 + kf * 32 + q * 8);

    #pragma unroll
    for (int p = 0; p < 3; ++p) {
        f32x4 acc[2][4] = {};
        #pragma unroll
        for (int kf = 0; kf < 4; ++kf) {
            bf16x8 b[4];
            #pragma unroll
            for (int fn = 0; fn < 4; ++fn)
                b[fn] = ldg_f32_b8(lw_in_w + (size_t)(p * 128 + wn + fn * 16 + ln) * 128 + kf * 32 + q * 8);
            #pragma unroll
            for (int fm = 0; fm < 2; ++fm)
                #pragma unroll
                for (int fn = 0; fn < 4; ++fn)
                    acc[fm][fn] = __builtin_amdgcn_mfma_f32_16x16x32_bf16(afr[kf][fm], b[fn], acc[fm][fn], 0, 0, 0);
        }
        #pragma unroll
        for (int fm = 0; fm < 2; ++fm)
            #pragma unroll
            for (int r = 0; r < 4; ++r) {
                int rl = wm + fm * 16 + q * 4 + r;
                #pragma unroll
                for (int fn = 0; fn < 4; ++fn) {
                    int col = wn + fn * 16 + ln;
                    unsigned short v = f2b(acc[fm][fn][r] + b_in[p * 128 + col]);
                    if (p == 0)      Qs[rl * 136 + col] = v;
                    else if (p == 1) Ks[rl * 136 + col] = v;
                    else             Vt[col * 72 + rl] = v;
                }
            }
    }
    __syncthreads();

    {   // ---- MFMA attention ----
        const int mh = wv >> 1, hq = wv & 1;
        unsigned short* P = &Pb[wv][0];
        #pragma unroll
        for (int hh = 0; hh < 4; ++hh) {
            const int h = hq * 4 + hh;
            f32x4 sacc[2][4] = {};
            bf16x8 az[2] = {}, bz[4] = {};
            if (q < 2) {
                #pragma unroll
                for (int fm = 0; fm < 2; ++fm)
                    az[fm] = *(const bf16x8*)&Qs[(mh * 32 + fm * 16 + ln) * 136 + h * 16 + q * 8];
                #pragma unroll
                for (int fn = 0; fn < 4; ++fn)
                    bz[fn] = *(const bf16x8*)&Ks[(fn * 16 + ln) * 136 + h * 16 + q * 8];
            }
            #pragma unroll
            for (int fm = 0; fm < 2; ++fm)
                #pragma unroll
                for (int fn = 0; fn < 4; ++fn)
                    sacc[fm][fn] = __builtin_amdgcn_mfma_f32_16x16x32_bf16(az[fm], bz[fn], sacc[fm][fn], 0, 0, 0);
            float invr[2][4];
            #pragma unroll
            for (int fm = 0; fm < 2; ++fm)
                #pragma unroll
                for (int r = 0; r < 4; ++r) {
                    int gi = mh * 32 + fm * 16 + q * 4 + r;
                    float mx = -1e30f;
                    #pragma unroll
                    for (int fn = 0; fn < 4; ++fn) {
                        int j = fn * 16 + ln;
                        float s = sacc[fm][fn][r] * 0.25f;
                        if (j > gi) s = -1e30f;
                        sacc[fm][fn][r] = s;
                        mx = fmaxf(mx, s);
                    }
                    #pragma unroll
                    for (int off = 1; off < 16; off <<= 1)
                        mx = fmaxf(mx, __shfl_xor(mx, off, 64));
                    float sum = 0.0f;
                    #pragma unroll
                    for (int fn = 0; fn < 4; ++fn) {
                        float p_ = __expf(sacc[fm][fn][r] - mx);
                        sacc[fm][fn][r] = p_;
                        sum += p_;
                    }
                    #pragma unroll
                    for (int off = 1; off < 16; off <<= 1)
                        sum += __shfl_xor(sum, off, 64);
                    invr[fm][r] = 1.0f / sum;
                    #pragma unroll
                    for (int fn = 0; fn < 4; ++fn)
                        P[(fm * 16 + q * 4 + r) * 72 + fn * 16 + ln] = f2b(sacc[fm][fn][r]);
                }
            f32x4 oacc[2] = {};
            #pragma unroll
            for (int kf2 = 0; kf2 < 2; ++kf2) {
                bf16x8 pa[2], vb;
                #pragma unroll
                for (int fm = 0; fm < 2; ++fm)
                    pa[fm] = *(const bf16x8*)&P[(fm * 16 + ln) * 72 + kf2 * 32 + q * 8];
                vb = *(const bf16x8*)&Vt[(h * 16 + ln) * 72 + kf2 * 32 + q * 8];
                #pragma unroll
                for (int fm = 0; fm < 2; ++fm)
                    oacc[fm] = __builtin_amdgcn_mfma_f32_16x16x32_bf16(pa[fm], vb, oacc[fm], 0, 0, 0);
            }
            #pragma unroll
            for (int fm = 0; fm < 2; ++fm)
                #pragma unroll
                for (int r = 0; r < 4; ++r)
                    Qs[(mh * 32 + fm * 16 + q * 4 + r) * 136 + h * 16 + ln] =
                        f2b(oacc[fm][r] * invr[fm][r]);
        }
    }
    __syncthreads();

    // ---- out-proj + residual(x) + LN1 ----
    f32x4 acc[2][4] = {};
    #pragma unroll
    for (int kf = 0; kf < 4; ++kf) {
        bf16x8 a[2], b[4];
        #pragma unroll
        for (int fm = 0; fm < 2; ++fm)
            a[fm] = *(const bf16x8*)&Qs[(wm + fm * 16 + ln) * 136 + kf * 32 + q * 8];
        #pragma unroll
        for (int fn = 0; fn < 4; ++fn)
            b[fn] = ldg_f32_b8(lw_out_w + (size_t)(wn + fn * 16 + ln) * 128 + kf * 32 + q * 8);
        #pragma unroll
        for (int fm = 0; fm < 2; ++fm)
            #pragma unroll
            for (int fn = 0; fn < 4; ++fn)
                acc[fm][fn] = __builtin_amdgcn_mfma_f32_16x16x32_bf16(a[fm], b[fn], acc[fm][fn], 0, 0, 0);
    }
    #pragma unroll
    for (int fm = 0; fm < 2; ++fm)
        #pragma unroll
        for (int r = 0; r < 4; ++r) {
            int rl = wm + fm * 16 + q * 4 + r;
            int row = m0 + rl;
            float s1 = 0.0f, s2 = 0.0f;
            #pragma unroll
            for (int fn = 0; fn < 4; ++fn) {
                int col = wn + fn * 16 + ln;
                float vv = acc[fm][fn][r] + b_out[col] + x[(size_t)row * 128 + col];
                acc[fm][fn][r] = vv;
                s1 += vv; s2 += vv * vv;
            }
            #pragma unroll
            for (int off = 1; off < 16; off <<= 1) {
                s1 += __shfl_xor(s1, off, 64);
                s2 += __shfl_xor(s2, off, 64);
            }
            if (ln == 0) { red[0][rl][wv & 1] = s1; red[1][rl][wv & 1] = s2; }
        }
    __syncthreads();
    #pragma unroll
    for (int fm = 0; fm < 2; ++fm)
        #pragma unroll
        for (int r = 0; r < 4; ++r) {
            int rl = wm + fm * 16 + q * 4 + r;
            int row = m0 + rl;
            float mu = (red[0][rl][0] + red[0][rl][1]) * (1.0f / 128.0f);
            float var = (red[1][rl][0] + red[1][rl][1]) * (1.0f / 128.0f) - mu * mu;
            float rs = rsqrtf(var + 1e-5f);
            #pragma unroll
            for (int fn = 0; fn < 4; ++fn) {
                int col = wn + fn * 16 + ln;
                float o = (acc[fm][fn][r] - mu) * rs * lng[col] + lnb[col];
                x1[(size_t)row * 128 + col] = o;
                x1b[(size_t)row * 128 + col] = f2b(o);
            }
        }
}

// ---------------------------------------------------------------------------
// Phase 2 (grid 768): bx<256 -> fused FFN (dbuf Hs); bx>=256 -> atb split-K.
// LDS overlaid via pool. ffn reads x1/x1b; atb reads snb/tnb, writes part
// (its own buffer; no alias with x1).
// ---------------------------------------------------------------------------
__global__ __launch_bounds__(256) void phase2(
    const unsigned short* __restrict__ x1b, const float* __restrict__ x1,
    const unsigned short* __restrict__ Wb,
    const float* __restrict__ b1, const float* __restrict__ b2,
    const float* __restrict__ lng, const float* __restrict__ lnb,
    float* __restrict__ x2,
    const unsigned short* __restrict__ snb, const unsigned short* __restrict__ tnb,
    float* __restrict__ part)
{
    __shared__ __align__(16) char pool[36864];
    __shared__ float red[2][64][2];
    const int tid = threadIdx.x;
    const int wv = tid >> 6, lane = tid & 63, ln = lane & 15, q = lane >> 4;

    if (blockIdx.x < 256) {   // ---- FFN role ----
        unsigned short* Xs = (unsigned short*)pool;            // 64*136
        unsigned short* Hs0 = (unsigned short*)(pool + 17408); // 64*72
        unsigned short* Hs1 = (unsigned short*)(pool + 26624); // 64*72
        const int t0 = blockIdx.x * 64;
        const int wm = (wv >> 1) * 32;
        const int wn1 = (wv & 1) * 32, wn2 = (wv & 1) * 64;
        const unsigned short* w1 = Wb;
        const unsigned short* w2 = Wb + 65536;

        const uint4* X4 = (const uint4*)(x1b + (size_t)t0 * 128);
        #pragma unroll
        for (int t = 0; t < 4; ++t) {
            int idx = tid + t * 256;
            int r = idx >> 4, c = idx & 15;
            *(uint4*)&Xs[r * 136 + c * 8] = X4[r * 16 + c];
        }
        __syncthreads();

        bf16x8 xfr[4][2];
        #pragma unroll
        for (int kf = 0; kf < 4; ++kf)
            #pragma unroll
            for (int fm = 0; fm < 2; ++fm)
                xfr[kf][fm] = *(const bf16x8*)&Xs[(wm + fm * 16 + ln) * 136 + kf * 32 + q * 8];

        f32x4 acc2[2][4] = {};
        for (int ch = 0; ch < 8; ++ch) {
            const int hc0 = ch * 64;
            unsigned short* Hb = (ch & 1) ? Hs1 : Hs0;
            f32x4 acc1[2][2] = {};
            #pragma unroll
            for (int kf = 0; kf < 4; ++kf) {
                bf16x8 b[2];
                #pragma unroll
                for (int fn = 0; fn < 2; ++fn)
                    b[fn] = *(const bf16x8*)&w1[(size_t)(hc0 + wn1 + fn * 16 + ln) * 128 + kf * 32 + q * 8];
                #pragma unroll
                for (int fm = 0; fm < 2; ++fm)
                    #pragma unroll
                    for (int fn = 0; fn < 2; ++fn)
                        acc1[fm][fn] = __builtin_amdgcn_mfma_f32_16x16x32_bf16(xfr[kf][fm], b[fn], acc1[fm][fn], 0, 0, 0);
            }
            #pragma unroll
            for (int fm = 0; fm < 2; ++fm)
                #pragma unroll
                for (int fn = 0; fn < 2; ++fn)
                    #pragma unroll
                    for (int r = 0; r < 4; ++r) {
                        int rl = wm + fm * 16 + q * 4 + r;
                        int col = wn1 + fn * 16 + ln;
                        Hb[rl * 72 + col] = f2b(gelu_tanh(acc1[fm][fn][r] + b1[hc0 + col]));
                    }
            __syncthreads();
            #pragma unroll
            for (int kf2 = 0; kf2 < 2; ++kf2) {
                bf16x8 a[2], b[4];
                #pragma unroll
                for (int fm = 0; fm < 2; ++fm)
                    a[fm] = *(const bf16x8*)&Hb[(wm + fm * 16 + ln) * 72 + kf2 * 32 + q * 8];
                #pragma unroll
                for (int fn = 0; fn < 4; ++fn)
                    b[fn] = *(const bf16x8*)&w2[(size_t)(wn2 + fn * 16 + ln) * 512 + hc0 + kf2 * 32 + q * 8];
                #pragma unroll
                for (int fm = 0; fm < 2; ++fm)
                    #pragma unroll
                    for (int fn = 0; fn < 4; ++fn)
                        acc2[fm][fn] = __builtin_amdgcn_mfma_f32_16x16x32_bf16(a[fm], b[fn], acc2[fm][fn], 0, 0, 0);
            }
        }
        #pragma unroll
        for (int fm = 0; fm < 2; ++fm)
            #pragma unroll
            for (int r = 0; r < 4; ++r) {
                int rl = wm + fm * 16 + q * 4 + r;
                int row = t0 + rl;
                float s1 = 0.0f, s2 = 0.0f;
                #pragma unroll
                for (int fn = 0; fn < 4; ++fn) {
                    int col = wn2 + fn * 16 + ln;
                    float vv = acc2[fm][fn][r] + b2[col] + x1[(size_t)row * 128 + col];
                    acc2[fm][fn][r] = vv;
                    s1 += vv; s2 += vv * vv;
                }
                #pragma unroll
                for (int off = 1; off < 16; off <<= 1) {
                    s1 += __shfl_xor(s1, off, 64);
                    s2 += __shfl_xor(s2, off, 64);
                }
                if (ln == 0) { red[0][rl][wv & 1] = s1; red[1][rl][wv & 1] = s2; }
            }
        __syncthreads();
        #pragma unroll
        for (int fm = 0; fm < 2; ++fm)
            #pragma unroll
            for (int r = 0; r < 4; ++r) {
                int rl = wm + fm * 16 + q * 4 + r;
                int row = t0 + rl;
                float mu = (red[0][rl][0] + red[0][rl][1]) * (1.0f / 128.0f);
                float var = (red[1][rl][0] + red[1][rl][1]) * (1.0f / 128.0f) - mu * mu;
                float rs = rsqrtf(var + 1e-5f);
                #pragma unroll
                for (int fn = 0; fn < 4; ++fn) {
                    int col = wn2 + fn * 16 + ln;
                    x2[(size_t)row * 128 + col] = (acc2[fm][fn][r] - mu) * rs * lng[col] + lnb[col];
                }
            }
        return;
    }

    // ---- atb split-K role ----
    {
        float* Ss = (float*)pool;              // 32*68
        float* Ts = (float*)(pool + 8704);     // 32*68
        const int idx2 = blockIdx.x - 256;     // 0..511
        const int d0 = (idx2 & 1) * 64, e0 = ((idx2 >> 1) & 1) * 64;
        const int z = idx2 >> 2;               // 0..127
        const int b = z >> 4, chunk = z & 15;
        const int tx = tid % 16, ty = tid / 16;
        const int jbase = chunk * (SS / ATB_SPLIT);
        float acc[4][4] = {};
        for (int j0 = jbase; j0 < jbase + SS / ATB_SPLIT; j0 += 32) {
            {
                int r = tid >> 3, c8 = (tid & 7) * 8;
                uint4 sv = *(const uint4*)&snb[(size_t)(b * SS + j0 + r) * 128 + d0 + c8];
                uint4 tv = *(const uint4*)&tnb[(size_t)(b * SS + j0 + r) * 128 + e0 + c8];
                const unsigned short* sp = (const unsigned short*)&sv;
                const unsigned short* tp = (const unsigned short*)&tv;
                #pragma unroll
                for (int c = 0; c < 8; ++c) {
                    Ss[r * 68 + c8 + c] = b2f(sp[c]);
                    Ts[r * 68 + c8 + c] = b2f(tp[c]);
                }
            }
            __syncthreads();
            #pragma unroll
            for (int kk = 0; kk < 32; ++kk) {
                float4 af = *(const float4*)&Ss[kk * 68 + ty * 4];
                float4 wf = *(const float4*)&Ts[kk * 68 + tx * 4];
                float a[4] = {af.x, af.y, af.z, af.w};
                float w[4] = {wf.x, wf.y, wf.z, wf.w};
                #pragma unroll
                for (int i = 0; i < 4; ++i)
                    #pragma unroll
                    for (int j = 0; j < 4; ++j)
                        acc[i][j] = fmaf(a[i], w[j], acc[i][j]);
            }
            __syncthreads();
        }
        float* pp = part + (size_t)(b * ATB_SPLIT + chunk) * 16384;
        #pragma unroll
        for (int i = 0; i < 4; ++i) {
            float4 ov = {acc[i][0], acc[i][1], acc[i][2], acc[i][3]};
            *(float4*)&pp[(size_t)(d0 + ty * 4 + i) * 128 + e0 + tx * 4] = ov;
        }
    }
}

// Mtb[b][e*128+d] = bf16( sum_chunk part[(b*16+c)*16384 + d*128 + e] )
__global__ __launch_bounds__(256) void atb_reduce_kernel(
    const float* __restrict__ part, unsigned short* __restrict__ Mtb)
{
    int i = blockIdx.x * 256 + threadIdx.x;   // 0..131071
    int b = i >> 14, rem = i & 16383;
    int e = rem >> 7, d = rem & 127;
    const float* pp = part + (size_t)b * ATB_SPLIT * 16384 + (size_t)d * 128 + e;
    float s = 0.0f;
    #pragma unroll
    for (int c = 0; c < ATB_SPLIT; ++c) s += pp[(size_t)c * 16384];
    Mtb[i] = f2b(s);
}

// ---------------------------------------------------------------------------
// sim[row] = (1/S) <snb@M_b, tnb>_row via MFMA; frags direct from global.
// ---------------------------------------------------------------------------
__global__ __launch_bounds__(256) void simgemm_kernel(
    const unsigned short* __restrict__ snb, const unsigned short* __restrict__ tnb,
    const unsigned short* __restrict__ Mtb, float* __restrict__ sim)
{
    __shared__ float red[64][2];
    const int tid = threadIdx.x, m0 = blockIdx.x * 64, b = m0 >> 11;
    const int wv = tid >> 6, lane = tid & 63, ln = lane & 15, q = lane >> 4;
    const int wm = (wv >> 1) * 32, wn = (wv & 1) * 64;

    f32x4 acc[2][4] = {};
    #pragma unroll
    for (int kf = 0; kf < 4; ++kf) {
        bf16x8 a[2], bb[4];
        #pragma unroll
        for (int fm = 0; fm < 2; ++fm)
            a[fm] = *(const bf16x8*)&snb[(size_t)(m0 + wm + fm * 16 + ln) * 128 + kf * 32 + q * 8];
        #pragma unroll
        for (int fn = 0; fn < 4; ++fn)
            bb[fn] = *(const bf16x8*)&Mtb[(size_t)b * 16384 + (size_t)(wn + fn * 16 + ln) * 128 + kf * 32 + q * 8];
        #pragma unroll
        for (int fm = 0; fm < 2; ++fm)
            #pragma unroll
            for (int fn = 0; fn < 4; ++fn)
                acc[fm][fn] = __builtin_amdgcn_mfma_f32_16x16x32_bf16(a[fm], bb[fn], acc[fm][fn], 0, 0, 0);
    }
    #pragma unroll
    for (int fm = 0; fm < 2; ++fm)
        #pragma unroll
        for (int r = 0; r < 4; ++r) {
            int rl = wm + fm * 16 + q * 4 + r;
            int row = m0 + rl;
            float s = 0.0f;
            #pragma unroll
            for (int fn = 0; fn < 4; ++fn) {
                int col = wn + fn * 16 + ln;
                s += acc[fm][fn][r] * b2f(tnb[(size_t)row * 128 + col]);
            }
            #pragma unroll
            for (int off = 1; off < 16; off <<= 1) s += __shfl_xor(s, off, 64);
            if (ln == 0) red[rl][wv & 1] = s;
        }
    __syncthreads();
    if (tid < 64) sim[m0 + tid] = (red[tid][0] + red[tid][1]) * (1.0f / (float)SS);
}

// ---------------------------------------------------------------------------
// Fused interaction block (self-converting weights).
// ---------------------------------------------------------------------------
__global__ __launch_bounds__(256) void inter_block(
    const unsigned short* __restrict__ seb, const unsigned short* __restrict__ teb,
    const float* __restrict__ Wint,  // (384,128) fp32
    const float* __restrict__ b_int,
    const float* __restrict__ Wio,   // (128,128) fp32
    const float* __restrict__ b_io,
    const float* __restrict__ sim, const float* __restrict__ x2,
    float* __restrict__ out)
{
    __shared__ unsigned short Qs[64 * 136];
    __shared__ unsigned short KVs[64 * 256];
    const int tid = threadIdx.x, s0 = blockIdx.x * 8;
    const int wv = tid >> 6, lane = tid & 63, ln = lane & 15, q = lane >> 4;
    const int wm = (wv >> 1) * 32, wn = (wv & 1) * 64;

    bf16x8 afr[4][2];
    #pragma unroll
    for (int kf = 0; kf < 4; ++kf)
        #pragma unroll
        for (int fm = 0; fm < 2; ++fm) {
            int rl = wm + fm * 16 + ln;
            size_t g = (size_t)(rl >> 3) * 2048 + s0 + (rl & 7);
            afr[kf][fm] = *(const bf16x8*)&seb[g * 128 + kf * 32 + q * 8];
        }

    #pragma unroll
    for (int p = 0; p < 3; ++p) {
        if (p == 1) {
            #pragma unroll
            for (int kf = 0; kf < 4; ++kf)
                #pragma unroll
                for (int fm = 0; fm < 2; ++fm) {
                    int rl = wm + fm * 16 + ln;
                    size_t g = (size_t)(rl >> 3) * 2048 + s0 + (rl & 7);
                    afr[kf][fm] = *(const bf16x8*)&teb[g * 128 + kf * 32 + q * 8];
                }
        }
        f32x4 acc[2][4] = {};
        #pragma unroll
        for (int kf = 0; kf < 4; ++kf) {
            bf16x8 b[4];
            #pragma unroll
            for (int fn = 0; fn < 4; ++fn)
                b[fn] = ldg_f32_b8(Wint + (size_t)(p * 128 + wn + fn * 16 + ln) * 128 + kf * 32 + q * 8);
            #pragma unroll
            for (int fm = 0; fm < 2; ++fm)
                #pragma unroll
                for (int fn = 0; fn < 4; ++fn)
                    acc[fm][fn] = __builtin_amdgcn_mfma_f32_16x16x32_bf16(afr[kf][fm], b[fn], acc[fm][fn], 0, 0, 0);
        }
        #pragma unroll
        for (int fm = 0; fm < 2; ++fm)
            #pragma unroll
            for (int r = 0; r < 4; ++r) {
                int rl = wm + fm * 16 + q * 4 + r;
                #pragma unroll
                for (int fn = 0; fn < 4; ++fn) {
                    int col = wn + fn * 16 + ln;
                    unsigned short v = f2b(acc[fm][fn][r] + b_int[p * 128 + col]);
                    if (p == 0) Qs[rl * 136 + col] = v;
                    else        KVs[rl * 256 + (p - 1) * 128 + col] = v;
                }
            }
        __syncthreads();
    }

    #pragma unroll
    for (int tt = 0; tt < 2; ++tt) {
        int task = tid + tt * 256;
        int ss = task >> 6, h = (task >> 3) & 7, i = task & 7;
        int rq = i * 8 + ss;
        float qr[16];
        {
            uint4 q0 = *(const uint4*)&Qs[rq * 136 + h * 16];
            uint4 q1 = *(const uint4*)&Qs[rq * 136 + h * 16 + 8];
            const unsigned short* p0 = (const unsigned short*)&q0;
            const unsigned short* p1 = (const unsigned short*)&q1;
            #pragma unroll
            for (int c = 0; c < 8; ++c) { qr[c] = b2f(p0[c]); qr[8 + c] = b2f(p1[c]); }
        }
        float sc[8];
        #pragma unroll
        for (int j = 0; j < 8; ++j) {
            uint4 k0 = *(const uint4*)&KVs[(j * 8 + ss) * 256 + h * 16];
            uint4 k1 = *(const uint4*)&KVs[(j * 8 + ss) * 256 + h * 16 + 8];
            const unsigned short* kp0 = (const unsigned short*)&k0;
            const unsigned short* kp1 = (const unsigned short*)&k1;
            float s = 0.0f;
            #pragma unroll
            for (int c = 0; c < 8; ++c) {
                s = fmaf(qr[c], b2f(kp0[c]), s);
                s = fmaf(qr[8 + c], b2f(kp1[c]), s);
            }
            sc[j] = s * 0.25f;
        }
        float mx = -1e30f;
        #pragma unroll
        for (int j = 0; j < 8; ++j) mx = fmaxf(mx, sc[j]);
        float pe[8], se = 0.0f;
        #pragma unroll
        for (int j = 0; j < 8; ++j) { pe[j] = __expf(sc[j] - mx); se += pe[j]; }
        float inv = 1.0f / se;
        float o[16] = {};
        #pragma unroll
        for (int j = 0; j < 8; ++j) {
            uint4 v0 = *(const uint4*)&KVs[(j * 8 + ss) * 256 + 128 + h * 16];
            uint4 v1 = *(const uint4*)&KVs[(j * 8 + ss) * 256 + 128 + h * 16 + 8];
            const unsigned short* vp0 = (const unsigned short*)&v0;
            const unsigned short* vp1 = (const unsigned short*)&v1;
            #pragma unroll
            for (int c = 0; c < 8; ++c) {
                o[c]     += pe[j] * b2f(vp0[c]);
                o[8 + c] += pe[j] * b2f(vp1[c]);
            }
        }
        ushort4 w0 = (ushort4){f2b(o[0]*inv),  f2b(o[1]*inv),  f2b(o[2]*inv),  f2b(o[3]*inv)};
        ushort4 w1 = (ushort4){f2b(o[4]*inv),  f2b(o[5]*inv),  f2b(o[6]*inv),  f2b(o[7]*inv)};
        ushort4 w2 = (ushort4){f2b(o[8]*inv),  f2b(o[9]*inv),  f2b(o[10]*inv), f2b(o[11]*inv)};
        ushort4 w3 = (ushort4){f2b(o[12]*inv), f2b(o[13]*inv), f2b(o[14]*inv), f2b(o[15]*inv)};
        *(ushort4*)&Qs[rq * 136 + h * 16]      = w0;
        *(ushort4*)&Qs[rq * 136 + h * 16 + 4]  = w1;
        *(ushort4*)&Qs[rq * 136 + h * 16 + 8]  = w2;
        *(ushort4*)&Qs[rq * 136 + h * 16 + 12] = w3;
    }
    __syncthreads();

    f32x4 acc[2][4] = {};
    #pragma unroll
    for (int kf = 0; kf < 4; ++kf) {
        bf16x8 a[2], b[4];
        #pragma unroll
        for (int fm = 0; fm < 2; ++fm)
            a[fm] = *(const bf16x8*)&Qs[(wm + fm * 16 + ln) * 136 + kf * 32 + q * 8];
        #pragma unroll
        for (int fn = 0; fn < 4; ++fn)
            b[fn] = ldg_f32_b8(Wio + (size_t)(wn + fn * 16 + ln) * 128 + kf * 32 + q * 8);
        #pragma unroll
        for (int fm = 0; fm < 2; ++fm)
            #pragma unroll
            for (int fn = 0; fn < 4; ++fn)
                acc[fm][fn] = __builtin_amdgcn_mfma_f32_16x16x32_bf16(a[fm], b[fn], acc[fm][fn], 0, 0, 0);
    }
    #pragma unroll
    for (int fm = 0; fm < 2; ++fm)
        #pragma unroll
        for (int r = 0; r < 4; ++r) {
            int rl = wm + fm * 16 + q * 4 + r;
            size_t g = (size_t)(rl >> 3) * 2048 + s0 + (rl & 7);
            float sc = sim[g];
            #pragma unroll
            for (int fn = 0; fn < 4; ++fn) {
                int col = wn + fn * 16 + ln;
                out[g * 128 + col] = (acc[fm][fn][r] + b_io[col]) * sc + x2[g * 128 + col];
            }
        }
}

// ---------------------------------------------------------------------------
extern "C" void kernel_launch(void* const* d_in, const int* in_sizes, int n_in,
                              void* d_out, int out_size, void* d_ws, size_t ws_size,
                              hipStream_t stream)
{
    const float* x        = (const float*)d_in[0];
    const float* spatial  = (const float*)d_in[1];
    const float* temporal = (const float*)d_in[2];
    const float* lw_in_w  = (const float*)d_in[3];
    const float* lw_in_b  = (const float*)d_in[4];
    const float* lw_out_w = (const float*)d_in[5];
    const float* lw_out_b = (const float*)d_in[6];
    const float* spat_w   = (const float*)d_in[7];
    const float* spat_b   = (const float*)d_in[8];
    const float* temp_w   = (const float*)d_in[9];
    const float* temp_b   = (const float*)d_in[10];
    const float* int_in_w = (const float*)d_in[11];
    const float* int_in_b = (const float*)d_in[12];
    const float* int_out_w= (const float*)d_in[13];
    const float* int_out_b= (const float*)d_in[14];
    const float* ffn_b1   = (const float*)d_in[16];
    const float* ffn_b2   = (const float*)d_in[18];
    const float* ln1_g    = (const float*)d_in[19];
    const float* ln1_b    = (const float*)d_in[20];
    const float* ln2_g    = (const float*)d_in[21];
    const float* ln2_b    = (const float*)d_in[22];
    float* out = (float*)d_out;

    // ---- workspace layout (bytes) ----
    char* base = (char*)d_ws;
    float*          x1   = (float*)(base + 0);                   // 8,388,608
    unsigned short* x1b  = (unsigned short*)(base + 8388608);    // 4,194,304
    float*          x2   = (float*)(base + 12582912);            // 8,388,608
    unsigned short* snb  = (unsigned short*)(base + 20971520);   // 4,194,304
    unsigned short* tnb  = (unsigned short*)(base + 25165824);   // 4,194,304
    unsigned short* seb  = (unsigned short*)(base + 29360128);   // 4,194,304
    unsigned short* teb  = (unsigned short*)(base + 33554432);   // 4,194,304
    unsigned short* Mtb  = (unsigned short*)(base + 37748736);   //   262,144
    float*          simb = (float*)(base + 38010880);            //    65,536
    unsigned short* Wb   = (unsigned short*)(base + 38076416);   //   262,144
    float*          part = (float*)(base + 38338560);            // 8,388,608 (own buffer — no alias)

    // 1: win_block (256) + convW (512) + stproj (512)
    phase1<<<1280, 256, 0, stream>>>(
        x, lw_in_w, lw_in_b, lw_out_w, lw_out_b, ln1_g, ln1_b, x1, x1b,
        (const float*)d_in[15], (const float*)d_in[17], Wb,
        spatial, temporal, spat_w, temp_w, spat_b, temp_b,
        snb, tnb, seb, teb);
    // 2: ffn (256) + atb split-K (512)
    phase2<<<768, 256, 0, stream>>>(
        x1b, x1, Wb, ffn_b1, ffn_b2, ln2_g, ln2_b, x2, snb, tnb, part);
    // 3: reduce + transpose -> bf16 M^T
    atb_reduce_kernel<<<512, 256, 0, stream>>>(part, Mtb);
    // 4: sim via MFMA
    simgemm_kernel<<<256, 256, 0, stream>>>(snb, tnb, Mtb, simb);
    // 5: interaction block
    inter_block<<<256, 256, 0, stream>>>(
        seb, teb, int_in_w, int_in_b, int_out_w, int_out_b, simb, x2, out);
}

// Round 12
// 231.650 us; speedup vs baseline: 1.2386x; 1.0452x over previous
//
#include <hip/hip_runtime.h>
#include <math.h>

#define BB 8
#define SS 2048
#define NTOK (BB * SS)   // 16384
#define ATB_SPLIT 16

using bf16x8 = __attribute__((ext_vector_type(8))) short;
using f32x4  = __attribute__((ext_vector_type(4))) float;

__device__ __forceinline__ float gelu_tanh(float x) {
    float y = 0.7978845608f * (x + 0.044715f * x * x * x);
    float e = __expf(2.0f * y);
    float t = 1.0f - 2.0f / (e + 1.0f);
    return 0.5f * x * (1.0f + t);
}
__device__ __forceinline__ unsigned short f2b(float f) {
    unsigned int u = __float_as_uint(f);
    u += 0x7FFFu + ((u >> 16) & 1u);
    return (unsigned short)(u >> 16);
}
__device__ __forceinline__ float b2f(unsigned short u) {
    return __uint_as_float((unsigned int)u << 16);
}
__device__ __forceinline__ bf16x8 ldg_f32_b8(const float* p) {
    float4 f0 = *(const float4*)p, f1 = *(const float4*)(p + 4);
    union { ushort4 u[2]; bf16x8 v; } r;
    r.u[0] = (ushort4){f2b(f0.x), f2b(f0.y), f2b(f0.z), f2b(f0.w)};
    r.u[1] = (ushort4){f2b(f1.x), f2b(f1.y), f2b(f1.z), f2b(f1.w)};
    return r.v;
}

// ---------------------------------------------------------------------------
// Phase 1 (grid 1280): bx<256 win_block | bx<768 convW(ffn) | bx<1280 stproj.
// ---------------------------------------------------------------------------
__global__ __launch_bounds__(256) void phase1(
    const float* __restrict__ x,
    const float* __restrict__ lw_in_w, const float* __restrict__ b_in,
    const float* __restrict__ lw_out_w, const float* __restrict__ b_out,
    const float* __restrict__ lng, const float* __restrict__ lnb,
    float* __restrict__ x1, unsigned short* __restrict__ x1b,
    const float* __restrict__ ffn_w1, const float* __restrict__ ffn_w2,
    unsigned short* __restrict__ Wb,
    const float* __restrict__ spatial, const float* __restrict__ temporal,
    const float* __restrict__ spat_w, const float* __restrict__ temp_w,
    const float* __restrict__ bsp, const float* __restrict__ btp,
    unsigned short* __restrict__ snb, unsigned short* __restrict__ tnb,
    unsigned short* __restrict__ seb, unsigned short* __restrict__ teb)
{
    __shared__ unsigned short Qs[64 * 136];   // Q; attn-out in-place
    __shared__ unsigned short Ks[64 * 136];
    __shared__ unsigned short Vt[128 * 72];
    __shared__ unsigned short Pb[4][32 * 72];
    __shared__ float red[2][64][2];
    const int tid = threadIdx.x;
    const int wv = tid >> 6, lane = tid & 63, ln = lane & 15, q = lane >> 4;

    if (blockIdx.x >= 768) {   // ---- stproj role ----
        const int idx2 = blockIdx.x - 768;
        const int y = idx2 >> 8;
        const int m0 = (idx2 & 255) * 64;
        const float* Af = y ? temporal : spatial;
        const float* Wf = y ? temp_w : spat_w;
        const float* bias = y ? btp : bsp;
        unsigned short* nb = y ? tnb : snb;
        unsigned short* raw = y ? teb : seb;
        const int wm = (wv >> 1) * 32, wn = (wv & 1) * 64;

        f32x4 acc[2][4] = {};
        #pragma unroll
        for (int kf = 0; kf < 4; ++kf) {
            bf16x8 a[2], b[4];
            #pragma unroll
            for (int fm = 0; fm < 2; ++fm)
                a[fm] = ldg_f32_b8(Af + (size_t)(m0 + wm + fm * 16 + ln) * 128 + kf * 32 + q * 8);
            #pragma unroll
            for (int fn = 0; fn < 4; ++fn)
                b[fn] = ldg_f32_b8(Wf + (size_t)(wn + fn * 16 + ln) * 128 + kf * 32 + q * 8);
            #pragma unroll
            for (int fm = 0; fm < 2; ++fm)
                #pragma unroll
                for (int fn = 0; fn < 4; ++fn)
                    acc[fm][fn] = __builtin_amdgcn_mfma_f32_16x16x32_bf16(a[fm], b[fn], acc[fm][fn], 0, 0, 0);
        }
        #pragma unroll
        for (int fm = 0; fm < 2; ++fm)
            #pragma unroll
            for (int r = 0; r < 4; ++r) {
                int rl = wm + fm * 16 + q * 4 + r;
                float s2 = 0.0f;
                #pragma unroll
                for (int fn = 0; fn < 4; ++fn) {
                    int col = wn + fn * 16 + ln;
                    float vv = acc[fm][fn][r] + bias[col];
                    acc[fm][fn][r] = vv;
                    s2 += vv * vv;
                }
                #pragma unroll
                for (int off = 1; off < 16; off <<= 1) s2 += __shfl_xor(s2, off, 64);
                if (ln == 0) red[0][rl][wv & 1] = s2;
            }
        __syncthreads();
        #pragma unroll
        for (int fm = 0; fm < 2; ++fm)
            #pragma unroll
            for (int r = 0; r < 4; ++r) {
                int rl = wm + fm * 16 + q * 4 + r;
                int row = m0 + rl;
                float inv = 1.0f / fmaxf(sqrtf(red[0][rl][0] + red[0][rl][1]), 1e-8f);
                #pragma unroll
                for (int fn = 0; fn < 4; ++fn) {
                    int col = wn + fn * 16 + ln;
                    float vv = acc[fm][fn][r];
                    nb[(size_t)row * 128 + col] = f2b(vv * inv);
                    raw[(size_t)row * 128 + col] = f2b(vv);
                }
            }
        return;
    }

    if (blockIdx.x >= 256) {   // ---- convW role ----
        int i = (blockIdx.x - 256) * 256 + tid;
        float v = (i < 65536) ? ffn_w1[i] : ffn_w2[i - 65536];
        Wb[i] = f2b(v);
        return;
    }

    // ---- win_block role ----
    const int m0 = blockIdx.x * 64;
    const int wm = (wv >> 1) * 32, wn = (wv & 1) * 64;

    bf16x8 afr[4][2];
    #pragma unroll
    for (int kf = 0; kf < 4; ++kf)
        #pragma unroll
        for (int fm = 0; fm < 2; ++fm)
            afr[kf][fm] = ldg_f32_b8(x + (size_t)(m0 + wm + fm * 16 + ln) * 128 + kf * 32 + q * 8);

    #pragma unroll
    for (int p = 0; p < 3; ++p) {
        f32x4 acc[2][4] = {};
        #pragma unroll
        for (int kf = 0; kf < 4; ++kf) {
            bf16x8 b[4];
            #pragma unroll
            for (int fn = 0; fn < 4; ++fn)
                b[fn] = ldg_f32_b8(lw_in_w + (size_t)(p * 128 + wn + fn * 16 + ln) * 128 + kf * 32 + q * 8);
            #pragma unroll
            for (int fm = 0; fm < 2; ++fm)
                #pragma unroll
                for (int fn = 0; fn < 4; ++fn)
                    acc[fm][fn] = __builtin_amdgcn_mfma_f32_16x16x32_bf16(afr[kf][fm], b[fn], acc[fm][fn], 0, 0, 0);
        }
        #pragma unroll
        for (int fm = 0; fm < 2; ++fm)
            #pragma unroll
            for (int r = 0; r < 4; ++r) {
                int rl = wm + fm * 16 + q * 4 + r;
                #pragma unroll
                for (int fn = 0; fn < 4; ++fn) {
                    int col = wn + fn * 16 + ln;
                    unsigned short v = f2b(acc[fm][fn][r] + b_in[p * 128 + col]);
                    if (p == 0)      Qs[rl * 136 + col] = v;
                    else if (p == 1) Ks[rl * 136 + col] = v;
                    else             Vt[col * 72 + rl] = v;
                }
            }
    }
    __syncthreads();

    {   // ---- MFMA attention ----
        const int mh = wv >> 1, hq = wv & 1;
        unsigned short* P = &Pb[wv][0];
        #pragma unroll
        for (int hh = 0; hh < 4; ++hh) {
            const int h = hq * 4 + hh;
            f32x4 sacc[2][4] = {};
            bf16x8 az[2] = {}, bz[4] = {};
            if (q < 2) {
                #pragma unroll
                for (int fm = 0; fm < 2; ++fm)
                    az[fm] = *(const bf16x8*)&Qs[(mh * 32 + fm * 16 + ln) * 136 + h * 16 + q * 8];
                #pragma unroll
                for (int fn = 0; fn < 4; ++fn)
                    bz[fn] = *(const bf16x8*)&Ks[(fn * 16 + ln) * 136 + h * 16 + q * 8];
            }
            #pragma unroll
            for (int fm = 0; fm < 2; ++fm)
                #pragma unroll
                for (int fn = 0; fn < 4; ++fn)
                    sacc[fm][fn] = __builtin_amdgcn_mfma_f32_16x16x32_bf16(az[fm], bz[fn], sacc[fm][fn], 0, 0, 0);
            float invr[2][4];
            #pragma unroll
            for (int fm = 0; fm < 2; ++fm)
                #pragma unroll
                for (int r = 0; r < 4; ++r) {
                    int gi = mh * 32 + fm * 16 + q * 4 + r;
                    float mx = -1e30f;
                    #pragma unroll
                    for (int fn = 0; fn < 4; ++fn) {
                        int j = fn * 16 + ln;
                        float s = sacc[fm][fn][r] * 0.25f;
                        if (j > gi) s = -1e30f;
                        sacc[fm][fn][r] = s;
                        mx = fmaxf(mx, s);
                    }
                    #pragma unroll
                    for (int off = 1; off < 16; off <<= 1)
                        mx = fmaxf(mx, __shfl_xor(mx, off, 64));
                    float sum = 0.0f;
                    #pragma unroll
                    for (int fn = 0; fn < 4; ++fn) {
                        float p_ = __expf(sacc[fm][fn][r] - mx);
                        sacc[fm][fn][r] = p_;
                        sum += p_;
                    }
                    #pragma unroll
                    for (int off = 1; off < 16; off <<= 1)
                        sum += __shfl_xor(sum, off, 64);
                    invr[fm][r] = 1.0f / sum;
                    #pragma unroll
                    for (int fn = 0; fn < 4; ++fn)
                        P[(fm * 16 + q * 4 + r) * 72 + fn * 16 + ln] = f2b(sacc[fm][fn][r]);
                }
            f32x4 oacc[2] = {};
            #pragma unroll
            for (int kf2 = 0; kf2 < 2; ++kf2) {
                bf16x8 pa[2], vb;
                #pragma unroll
                for (int fm = 0; fm < 2; ++fm)
                    pa[fm] = *(const bf16x8*)&P[(fm * 16 + ln) * 72 + kf2 * 32 + q * 8];
                vb = *(const bf16x8*)&Vt[(h * 16 + ln) * 72 + kf2 * 32 + q * 8];
                #pragma unroll
                for (int fm = 0; fm < 2; ++fm)
                    oacc[fm] = __builtin_amdgcn_mfma_f32_16x16x32_bf16(pa[fm], vb, oacc[fm], 0, 0, 0);
            }
            #pragma unroll
            for (int fm = 0; fm < 2; ++fm)
                #pragma unroll
                for (int r = 0; r < 4; ++r)
                    Qs[(mh * 32 + fm * 16 + q * 4 + r) * 136 + h * 16 + ln] =
                        f2b(oacc[fm][r] * invr[fm][r]);
        }
    }
    __syncthreads();

    // ---- out-proj + residual(x) + LN1 ----
    f32x4 acc[2][4] = {};
    #pragma unroll
    for (int kf = 0; kf < 4; ++kf) {
        bf16x8 a[2], b[4];
        #pragma unroll
        for (int fm = 0; fm < 2; ++fm)
            a[fm] = *(const bf16x8*)&Qs[(wm + fm * 16 + ln) * 136 + kf * 32 + q * 8];
        #pragma unroll
        for (int fn = 0; fn < 4; ++fn)
            b[fn] = ldg_f32_b8(lw_out_w + (size_t)(wn + fn * 16 + ln) * 128 + kf * 32 + q * 8);
        #pragma unroll
        for (int fm = 0; fm < 2; ++fm)
            #pragma unroll
            for (int fn = 0; fn < 4; ++fn)
                acc[fm][fn] = __builtin_amdgcn_mfma_f32_16x16x32_bf16(a[fm], b[fn], acc[fm][fn], 0, 0, 0);
    }
    #pragma unroll
    for (int fm = 0; fm < 2; ++fm)
        #pragma unroll
        for (int r = 0; r < 4; ++r) {
            int rl = wm + fm * 16 + q * 4 + r;
            int row = m0 + rl;
            float s1 = 0.0f, s2 = 0.0f;
            #pragma unroll
            for (int fn = 0; fn < 4; ++fn) {
                int col = wn + fn * 16 + ln;
                float vv = acc[fm][fn][r] + b_out[col] + x[(size_t)row * 128 + col];
                acc[fm][fn][r] = vv;
                s1 += vv; s2 += vv * vv;
            }
            #pragma unroll
            for (int off = 1; off < 16; off <<= 1) {
                s1 += __shfl_xor(s1, off, 64);
                s2 += __shfl_xor(s2, off, 64);
            }
            if (ln == 0) { red[0][rl][wv & 1] = s1; red[1][rl][wv & 1] = s2; }
        }
    __syncthreads();
    #pragma unroll
    for (int fm = 0; fm < 2; ++fm)
        #pragma unroll
        for (int r = 0; r < 4; ++r) {
            int rl = wm + fm * 16 + q * 4 + r;
            int row = m0 + rl;
            float mu = (red[0][rl][0] + red[0][rl][1]) * (1.0f / 128.0f);
            float var = (red[1][rl][0] + red[1][rl][1]) * (1.0f / 128.0f) - mu * mu;
            float rs = rsqrtf(var + 1e-5f);
            #pragma unroll
            for (int fn = 0; fn < 4; ++fn) {
                int col = wn + fn * 16 + ln;
                float o = (acc[fm][fn][r] - mu) * rs * lng[col] + lnb[col];
                x1[(size_t)row * 128 + col] = o;
                x1b[(size_t)row * 128 + col] = f2b(o);
            }
        }
}

// ---------------------------------------------------------------------------
// Phase 2 (grid 768): bx<256 -> fused FFN (dbuf Hs, A-frags from LDS);
//                     bx>=256 -> atb split-K via MFMA (transposed LDS stage).
// ---------------------------------------------------------------------------
__global__ __launch_bounds__(256) void phase2(
    const unsigned short* __restrict__ x1b, const float* __restrict__ x1,
    const unsigned short* __restrict__ Wb,
    const float* __restrict__ b1, const float* __restrict__ b2,
    const float* __restrict__ lng, const float* __restrict__ lnb,
    float* __restrict__ x2,
    const unsigned short* __restrict__ snb, const unsigned short* __restrict__ tnb,
    float* __restrict__ part)
{
    __shared__ __align__(16) char pool[36864];
    __shared__ float red[2][64][2];
    const int tid = threadIdx.x;
    const int wv = tid >> 6, lane = tid & 63, ln = lane & 15, q = lane >> 4;

    if (blockIdx.x < 256) {   // ---- FFN role ----
        unsigned short* Xs = (unsigned short*)pool;            // 64*136
        unsigned short* Hs0 = (unsigned short*)(pool + 17408); // 64*72
        unsigned short* Hs1 = (unsigned short*)(pool + 26624); // 64*72
        const int t0 = blockIdx.x * 64;
        const int wm = (wv >> 1) * 32;
        const int wn1 = (wv & 1) * 32, wn2 = (wv & 1) * 64;
        const unsigned short* w1 = Wb;
        const unsigned short* w2 = Wb + 65536;

        const uint4* X4 = (const uint4*)(x1b + (size_t)t0 * 128);
        #pragma unroll
        for (int t = 0; t < 4; ++t) {
            int idx = tid + t * 256;
            int r = idx >> 4, c = idx & 15;
            *(uint4*)&Xs[r * 136 + c * 8] = X4[r * 16 + c];
        }
        __syncthreads();

        f32x4 acc2[2][4] = {};
        for (int ch = 0; ch < 8; ++ch) {
            const int hc0 = ch * 64;
            unsigned short* Hb = (ch & 1) ? Hs1 : Hs0;
            f32x4 acc1[2][2] = {};
            #pragma unroll
            for (int kf = 0; kf < 4; ++kf) {
                bf16x8 a[2], b[2];
                #pragma unroll
                for (int fm = 0; fm < 2; ++fm)
                    a[fm] = *(const bf16x8*)&Xs[(wm + fm * 16 + ln) * 136 + kf * 32 + q * 8];
                #pragma unroll
                for (int fn = 0; fn < 2; ++fn)
                    b[fn] = *(const bf16x8*)&w1[(size_t)(hc0 + wn1 + fn * 16 + ln) * 128 + kf * 32 + q * 8];
                #pragma unroll
                for (int fm = 0; fm < 2; ++fm)
                    #pragma unroll
                    for (int fn = 0; fn < 2; ++fn)
                        acc1[fm][fn] = __builtin_amdgcn_mfma_f32_16x16x32_bf16(a[fm], b[fn], acc1[fm][fn], 0, 0, 0);
            }
            #pragma unroll
            for (int fm = 0; fm < 2; ++fm)
                #pragma unroll
                for (int fn = 0; fn < 2; ++fn)
                    #pragma unroll
                    for (int r = 0; r < 4; ++r) {
                        int rl = wm + fm * 16 + q * 4 + r;
                        int col = wn1 + fn * 16 + ln;
                        Hb[rl * 72 + col] = f2b(gelu_tanh(acc1[fm][fn][r] + b1[hc0 + col]));
                    }
            __syncthreads();
            #pragma unroll
            for (int kf2 = 0; kf2 < 2; ++kf2) {
                bf16x8 a[2], b[4];
                #pragma unroll
                for (int fm = 0; fm < 2; ++fm)
                    a[fm] = *(const bf16x8*)&Hb[(wm + fm * 16 + ln) * 72 + kf2 * 32 + q * 8];
                #pragma unroll
                for (int fn = 0; fn < 4; ++fn)
                    b[fn] = *(const bf16x8*)&w2[(size_t)(wn2 + fn * 16 + ln) * 512 + hc0 + kf2 * 32 + q * 8];
                #pragma unroll
                for (int fm = 0; fm < 2; ++fm)
                    #pragma unroll
                    for (int fn = 0; fn < 4; ++fn)
                        acc2[fm][fn] = __builtin_amdgcn_mfma_f32_16x16x32_bf16(a[fm], b[fn], acc2[fm][fn], 0, 0, 0);
            }
        }
        #pragma unroll
        for (int fm = 0; fm < 2; ++fm)
            #pragma unroll
            for (int r = 0; r < 4; ++r) {
                int rl = wm + fm * 16 + q * 4 + r;
                int row = t0 + rl;
                float s1 = 0.0f, s2 = 0.0f;
                #pragma unroll
                for (int fn = 0; fn < 4; ++fn) {
                    int col = wn2 + fn * 16 + ln;
                    float vv = acc2[fm][fn][r] + b2[col] + x1[(size_t)row * 128 + col];
                    acc2[fm][fn][r] = vv;
                    s1 += vv; s2 += vv * vv;
                }
                #pragma unroll
                for (int off = 1; off < 16; off <<= 1) {
                    s1 += __shfl_xor(s1, off, 64);
                    s2 += __shfl_xor(s2, off, 64);
                }
                if (ln == 0) { red[0][rl][wv & 1] = s1; red[1][rl][wv & 1] = s2; }
            }
        __syncthreads();
        #pragma unroll
        for (int fm = 0; fm < 2; ++fm)
            #pragma unroll
            for (int r = 0; r < 4; ++r) {
                int rl = wm + fm * 16 + q * 4 + r;
                int row = t0 + rl;
                float mu = (red[0][rl][0] + red[0][rl][1]) * (1.0f / 128.0f);
                float var = (red[1][rl][0] + red[1][rl][1]) * (1.0f / 128.0f) - mu * mu;
                float rs = rsqrtf(var + 1e-5f);
                #pragma unroll
                for (int fn = 0; fn < 4; ++fn) {
                    int col = wn2 + fn * 16 + ln;
                    x2[(size_t)row * 128 + col] = (acc2[fm][fn][r] - mu) * rs * lng[col] + lnb[col];
                }
            }
        return;
    }

    // ---- atb split-K role (MFMA) ----
    {
        unsigned short* Sst = (unsigned short*)pool;            // [64 d][136 j-pitch]
        unsigned short* Tst = (unsigned short*)(pool + 17408);  // [64 e][136 j-pitch]
        const int idx2 = blockIdx.x - 256;     // 0..511
        const int d0 = (idx2 & 1) * 64, e0 = ((idx2 >> 1) & 1) * 64;
        const int z = idx2 >> 2;               // 0..127
        const int b = z >> 4, chunk = z & 15;
        const size_t rowb = (size_t)(b * SS + chunk * 128);

        // stage transposed: Sst[d][j] = snb[rowb+j][d0+d], j-fastest lanes
        #pragma unroll
        for (int it = 0; it < 4; ++it) {
            int j = (tid & 31) + it * 32;
            int c8 = (tid >> 5) * 8;
            uint4 sv = *(const uint4*)&snb[(rowb + j) * 128 + d0 + c8];
            uint4 tv = *(const uint4*)&tnb[(rowb + j) * 128 + e0 + c8];
            const unsigned short* sp = (const unsigned short*)&sv;
            const unsigned short* tp = (const unsigned short*)&tv;
            #pragma unroll
            for (int c = 0; c < 8; ++c) {
                Sst[(c8 + c) * 136 + j] = sp[c];
                Tst[(c8 + c) * 136 + j] = tp[c];
            }
        }
        __syncthreads();

        const int wm = (wv >> 1) * 32, wn = (wv & 1) * 32;
        f32x4 acc[2][2] = {};
        #pragma unroll
        for (int kf = 0; kf < 4; ++kf) {
            bf16x8 a[2], bb[2];
            #pragma unroll
            for (int fm = 0; fm < 2; ++fm)
                a[fm] = *(const bf16x8*)&Sst[(wm + fm * 16 + ln) * 136 + kf * 32 + q * 8];
            #pragma unroll
            for (int fn = 0; fn < 2; ++fn)
                bb[fn] = *(const bf16x8*)&Tst[(wn + fn * 16 + ln) * 136 + kf * 32 + q * 8];
            #pragma unroll
            for (int fm = 0; fm < 2; ++fm)
                #pragma unroll
                for (int fn = 0; fn < 2; ++fn)
                    acc[fm][fn] = __builtin_amdgcn_mfma_f32_16x16x32_bf16(a[fm], bb[fn], acc[fm][fn], 0, 0, 0);
        }
        float* pp = part + (size_t)(b * ATB_SPLIT + chunk) * 16384;
        #pragma unroll
        for (int fm = 0; fm < 2; ++fm)
            #pragma unroll
            for (int r = 0; r < 4; ++r) {
                int dd = d0 + wm + fm * 16 + q * 4 + r;
                #pragma unroll
                for (int fn = 0; fn < 2; ++fn) {
                    int ee = e0 + wn + fn * 16 + ln;
                    pp[(size_t)dd * 128 + ee] = acc[fm][fn][r];
                }
            }
    }
}

// Mtb[b][e*128+d] = bf16( sum_chunk part[(b*16+c)*16384 + d*128 + e] )
__global__ __launch_bounds__(256) void atb_reduce_kernel(
    const float* __restrict__ part, unsigned short* __restrict__ Mtb)
{
    int i = blockIdx.x * 256 + threadIdx.x;   // 0..131071
    int b = i >> 14, rem = i & 16383;
    int e = rem >> 7, d = rem & 127;
    const float* pp = part + (size_t)b * ATB_SPLIT * 16384 + (size_t)d * 128 + e;
    float s = 0.0f;
    #pragma unroll
    for (int c = 0; c < ATB_SPLIT; ++c) s += pp[(size_t)c * 16384];
    Mtb[i] = f2b(s);
}

// ---------------------------------------------------------------------------
// sim[row] = (1/S) <snb@M_b, tnb>_row via MFMA; frags direct from global.
// ---------------------------------------------------------------------------
__global__ __launch_bounds__(256) void simgemm_kernel(
    const unsigned short* __restrict__ snb, const unsigned short* __restrict__ tnb,
    const unsigned short* __restrict__ Mtb, float* __restrict__ sim)
{
    __shared__ float red[64][2];
    const int tid = threadIdx.x, m0 = blockIdx.x * 64, b = m0 >> 11;
    const int wv = tid >> 6, lane = tid & 63, ln = lane & 15, q = lane >> 4;
    const int wm = (wv >> 1) * 32, wn = (wv & 1) * 64;

    f32x4 acc[2][4] = {};
    #pragma unroll
    for (int kf = 0; kf < 4; ++kf) {
        bf16x8 a[2], bb[4];
        #pragma unroll
        for (int fm = 0; fm < 2; ++fm)
            a[fm] = *(const bf16x8*)&snb[(size_t)(m0 + wm + fm * 16 + ln) * 128 + kf * 32 + q * 8];
        #pragma unroll
        for (int fn = 0; fn < 4; ++fn)
            bb[fn] = *(const bf16x8*)&Mtb[(size_t)b * 16384 + (size_t)(wn + fn * 16 + ln) * 128 + kf * 32 + q * 8];
        #pragma unroll
        for (int fm = 0; fm < 2; ++fm)
            #pragma unroll
            for (int fn = 0; fn < 4; ++fn)
                acc[fm][fn] = __builtin_amdgcn_mfma_f32_16x16x32_bf16(a[fm], bb[fn], acc[fm][fn], 0, 0, 0);
    }
    #pragma unroll
    for (int fm = 0; fm < 2; ++fm)
        #pragma unroll
        for (int r = 0; r < 4; ++r) {
            int rl = wm + fm * 16 + q * 4 + r;
            int row = m0 + rl;
            float s = 0.0f;
            #pragma unroll
            for (int fn = 0; fn < 4; ++fn) {
                int col = wn + fn * 16 + ln;
                s += acc[fm][fn][r] * b2f(tnb[(size_t)row * 128 + col]);
            }
            #pragma unroll
            for (int off = 1; off < 16; off <<= 1) s += __shfl_xor(s, off, 64);
            if (ln == 0) red[rl][wv & 1] = s;
        }
    __syncthreads();
    if (tid < 64) sim[m0 + tid] = (red[tid][0] + red[tid][1]) * (1.0f / (float)SS);
}

// ---------------------------------------------------------------------------
// Fused interaction block (self-converting weights).
// ---------------------------------------------------------------------------
__global__ __launch_bounds__(256) void inter_block(
    const unsigned short* __restrict__ seb, const unsigned short* __restrict__ teb,
    const float* __restrict__ Wint,  // (384,128) fp32
    const float* __restrict__ b_int,
    const float* __restrict__ Wio,   // (128,128) fp32
    const float* __restrict__ b_io,
    const float* __restrict__ sim, const float* __restrict__ x2,
    float* __restrict__ out)
{
    __shared__ unsigned short Qs[64 * 136];
    __shared__ unsigned short KVs[64 * 256];
    const int tid = threadIdx.x, s0 = blockIdx.x * 8;
    const int wv = tid >> 6, lane = tid & 63, ln = lane & 15, q = lane >> 4;
    const int wm = (wv >> 1) * 32, wn = (wv & 1) * 64;

    bf16x8 afr[4][2];
    #pragma unroll
    for (int kf = 0; kf < 4; ++kf)
        #pragma unroll
        for (int fm = 0; fm < 2; ++fm) {
            int rl = wm + fm * 16 + ln;
            size_t g = (size_t)(rl >> 3) * 2048 + s0 + (rl & 7);
            afr[kf][fm] = *(const bf16x8*)&seb[g * 128 + kf * 32 + q * 8];
        }

    #pragma unroll
    for (int p = 0; p < 3; ++p) {
        if (p == 1) {
            #pragma unroll
            for (int kf = 0; kf < 4; ++kf)
                #pragma unroll
                for (int fm = 0; fm < 2; ++fm) {
                    int rl = wm + fm * 16 + ln;
                    size_t g = (size_t)(rl >> 3) * 2048 + s0 + (rl & 7);
                    afr[kf][fm] = *(const bf16x8*)&teb[g * 128 + kf * 32 + q * 8];
                }
        }
        f32x4 acc[2][4] = {};
        #pragma unroll
        for (int kf = 0; kf < 4; ++kf) {
            bf16x8 b[4];
            #pragma unroll
            for (int fn = 0; fn < 4; ++fn)
                b[fn] = ldg_f32_b8(Wint + (size_t)(p * 128 + wn + fn * 16 + ln) * 128 + kf * 32 + q * 8);
            #pragma unroll
            for (int fm = 0; fm < 2; ++fm)
                #pragma unroll
                for (int fn = 0; fn < 4; ++fn)
                    acc[fm][fn] = __builtin_amdgcn_mfma_f32_16x16x32_bf16(afr[kf][fm], b[fn], acc[fm][fn], 0, 0, 0);
        }
        #pragma unroll
        for (int fm = 0; fm < 2; ++fm)
            #pragma unroll
            for (int r = 0; r < 4; ++r) {
                int rl = wm + fm * 16 + q * 4 + r;
                #pragma unroll
                for (int fn = 0; fn < 4; ++fn) {
                    int col = wn + fn * 16 + ln;
                    unsigned short v = f2b(acc[fm][fn][r] + b_int[p * 128 + col]);
                    if (p == 0) Qs[rl * 136 + col] = v;
                    else        KVs[rl * 256 + (p - 1) * 128 + col] = v;
                }
            }
        __syncthreads();
    }

    #pragma unroll
    for (int tt = 0; tt < 2; ++tt) {
        int task = tid + tt * 256;
        int ss = task >> 6, h = (task >> 3) & 7, i = task & 7;
        int rq = i * 8 + ss;
        float qr[16];
        {
            uint4 q0 = *(const uint4*)&Qs[rq * 136 + h * 16];
            uint4 q1 = *(const uint4*)&Qs[rq * 136 + h * 16 + 8];
            const unsigned short* p0 = (const unsigned short*)&q0;
            const unsigned short* p1 = (const unsigned short*)&q1;
            #pragma unroll
            for (int c = 0; c < 8; ++c) { qr[c] = b2f(p0[c]); qr[8 + c] = b2f(p1[c]); }
        }
        float sc[8];
        #pragma unroll
        for (int j = 0; j < 8; ++j) {
            uint4 k0 = *(const uint4*)&KVs[(j * 8 + ss) * 256 + h * 16];
            uint4 k1 = *(const uint4*)&KVs[(j * 8 + ss) * 256 + h * 16 + 8];
            const unsigned short* kp0 = (const unsigned short*)&k0;
            const unsigned short* kp1 = (const unsigned short*)&k1;
            float s = 0.0f;
            #pragma unroll
            for (int c = 0; c < 8; ++c) {
                s = fmaf(qr[c], b2f(kp0[c]), s);
                s = fmaf(qr[8 + c], b2f(kp1[c]), s);
            }
            sc[j] = s * 0.25f;
        }
        float mx = -1e30f;
        #pragma unroll
        for (int j = 0; j < 8; ++j) mx = fmaxf(mx, sc[j]);
        float pe[8], se = 0.0f;
        #pragma unroll
        for (int j = 0; j < 8; ++j) { pe[j] = __expf(sc[j] - mx); se += pe[j]; }
        float inv = 1.0f / se;
        float o[16] = {};
        #pragma unroll
        for (int j = 0; j < 8; ++j) {
            uint4 v0 = *(const uint4*)&KVs[(j * 8 + ss) * 256 + 128 + h * 16];
            uint4 v1 = *(const uint4*)&KVs[(j * 8 + ss) * 256 + 128 + h * 16 + 8];
            const unsigned short* vp0 = (const unsigned short*)&v0;
            const unsigned short* vp1 = (const unsigned short*)&v1;
            #pragma unroll
            for (int c = 0; c < 8; ++c) {
                o[c]     += pe[j] * b2f(vp0[c]);
                o[8 + c] += pe[j] * b2f(vp1[c]);
            }
        }
        ushort4 w0 = (ushort4){f2b(o[0]*inv),  f2b(o[1]*inv),  f2b(o[2]*inv),  f2b(o[3]*inv)};
        ushort4 w1 = (ushort4){f2b(o[4]*inv),  f2b(o[5]*inv),  f2b(o[6]*inv),  f2b(o[7]*inv)};
        ushort4 w2 = (ushort4){f2b(o[8]*inv),  f2b(o[9]*inv),  f2b(o[10]*inv), f2b(o[11]*inv)};
        ushort4 w3 = (ushort4){f2b(o[12]*inv), f2b(o[13]*inv), f2b(o[14]*inv), f2b(o[15]*inv)};
        *(ushort4*)&Qs[rq * 136 + h * 16]      = w0;
        *(ushort4*)&Qs[rq * 136 + h * 16 + 4]  = w1;
        *(ushort4*)&Qs[rq * 136 + h * 16 + 8]  = w2;
        *(ushort4*)&Qs[rq * 136 + h * 16 + 12] = w3;
    }
    __syncthreads();

    f32x4 acc[2][4] = {};
    #pragma unroll
    for (int kf = 0; kf < 4; ++kf) {
        bf16x8 a[2], b[4];
        #pragma unroll
        for (int fm = 0; fm < 2; ++fm)
            a[fm] = *(const bf16x8*)&Qs[(wm + fm * 16 + ln) * 136 + kf * 32 + q * 8];
        #pragma unroll
        for (int fn = 0; fn < 4; ++fn)
            b[fn] = ldg_f32_b8(Wio + (size_t)(wn + fn * 16 + ln) * 128 + kf * 32 + q * 8);
        #pragma unroll
        for (int fm = 0; fm < 2; ++fm)
            #pragma unroll
            for (int fn = 0; fn < 4; ++fn)
                acc[fm][fn] = __builtin_amdgcn_mfma_f32_16x16x32_bf16(a[fm], b[fn], acc[fm][fn], 0, 0, 0);
    }
    #pragma unroll
    for (int fm = 0; fm < 2; ++fm)
        #pragma unroll
        for (int r = 0; r < 4; ++r) {
            int rl = wm + fm * 16 + q * 4 + r;
            size_t g = (size_t)(rl >> 3) * 2048 + s0 + (rl & 7);
            float sc = sim[g];
            #pragma unroll
            for (int fn = 0; fn < 4; ++fn) {
                int col = wn + fn * 16 + ln;
                out[g * 128 + col] = (acc[fm][fn][r] + b_io[col]) * sc + x2[g * 128 + col];
            }
        }
}

// ---------------------------------------------------------------------------
extern "C" void kernel_launch(void* const* d_in, const int* in_sizes, int n_in,
                              void* d_out, int out_size, void* d_ws, size_t ws_size,
                              hipStream_t stream)
{
    const float* x        = (const float*)d_in[0];
    const float* spatial  = (const float*)d_in[1];
    const float* temporal = (const float*)d_in[2];
    const float* lw_in_w  = (const float*)d_in[3];
    const float* lw_in_b  = (const float*)d_in[4];
    const float* lw_out_w = (const float*)d_in[5];
    const float* lw_out_b = (const float*)d_in[6];
    const float* spat_w   = (const float*)d_in[7];
    const float* spat_b   = (const float*)d_in[8];
    const float* temp_w   = (const float*)d_in[9];
    const float* temp_b   = (const float*)d_in[10];
    const float* int_in_w = (const float*)d_in[11];
    const float* int_in_b = (const float*)d_in[12];
    const float* int_out_w= (const float*)d_in[13];
    const float* int_out_b= (const float*)d_in[14];
    const float* ffn_b1   = (const float*)d_in[16];
    const float* ffn_b2   = (const float*)d_in[18];
    const float* ln1_g    = (const float*)d_in[19];
    const float* ln1_b    = (const float*)d_in[20];
    const float* ln2_g    = (const float*)d_in[21];
    const float* ln2_b    = (const float*)d_in[22];
    float* out = (float*)d_out;

    // ---- workspace layout (bytes) ----
    char* base = (char*)d_ws;
    float*          x1   = (float*)(base + 0);                   // 8,388,608
    unsigned short* x1b  = (unsigned short*)(base + 8388608);    // 4,194,304
    float*          x2   = (float*)(base + 12582912);            // 8,388,608
    unsigned short* snb  = (unsigned short*)(base + 20971520);   // 4,194,304
    unsigned short* tnb  = (unsigned short*)(base + 25165824);   // 4,194,304
    unsigned short* seb  = (unsigned short*)(base + 29360128);   // 4,194,304
    unsigned short* teb  = (unsigned short*)(base + 33554432);   // 4,194,304
    unsigned short* Mtb  = (unsigned short*)(base + 37748736);   //   262,144
    float*          simb = (float*)(base + 38010880);            //    65,536
    unsigned short* Wb   = (unsigned short*)(base + 38076416);   //   262,144
    float*          part = (float*)(base + 38338560);            // 8,388,608

    // 1: win_block (256) + convW (512) + stproj (512)
    phase1<<<1280, 256, 0, stream>>>(
        x, lw_in_w, lw_in_b, lw_out_w, lw_out_b, ln1_g, ln1_b, x1, x1b,
        (const float*)d_in[15], (const float*)d_in[17], Wb,
        spatial, temporal, spat_w, temp_w, spat_b, temp_b,
        snb, tnb, seb, teb);
    // 2: ffn (256) + atb split-K MFMA (512)
    phase2<<<768, 256, 0, stream>>>(
        x1b, x1, Wb, ffn_b1, ffn_b2, ln2_g, ln2_b, x2, snb, tnb, part);
    // 3: reduce + transpose -> bf16 M^T
    atb_reduce_kernel<<<512, 256, 0, stream>>>(part, Mtb);
    // 4: sim via MFMA
    simgemm_kernel<<<256, 256, 0, stream>>>(snb, tnb, Mtb, simb);
    // 5: interaction block
    inter_block<<<256, 256, 0, stream>>>(
        seb, teb, int_in_w, int_in_b, int_out_w, int_out_b, simb, x2, out);
}